// Round 1
// baseline (4816.642 us; speedup 1.0000x reference)
//
#include <hip/hip_runtime.h>
#include <hip/hip_bf16.h>
#include <stdint.h>

typedef float f32x4 __attribute__((ext_vector_type(4)));
typedef short s16x8 __attribute__((ext_vector_type(8)));
typedef unsigned short u16;

#define M_ROWS 4096
#define DIM    768
#define VOCAB  50257
#define VPAD   50272           // 1571 * 32
#define NTILES_V 1571
#define SV     8
#define TILES_PER_SV 197       // ceil(1571/8)

// ws layout (bytes)
#define OFF_XB     0ull
#define OFF_WVB    6291456ull          // bf16 [VPAD][768]
#define OFF_WVT    83509248ull         // bf16 blocked [1571][768][32]
#define OFF_WLB    160727040ull        // bf16 [768][768]
#define OFF_H      161906688ull        // bf16 [4096][768]
#define OFF_OPART  168198144ull        // f32 [64][8][64][768]
#define OFF_ML     268861440ull        // f32 [64][8][2][64]

__device__ __forceinline__ u16 f2bf(float f) {
    union { float f; unsigned u; } x; x.f = f;
    return (u16)((x.u + 0x7fffu + ((x.u >> 16) & 1u)) >> 16);
}

// ---------------- K0a: elementwise f32 -> bf16 cast ----------------
__global__ __launch_bounds__(256) void cast_bf16(const float* __restrict__ src,
                                                 u16* __restrict__ dst, int n4) {
    int i = blockIdx.x * 256 + threadIdx.x;
    if (i >= n4) return;
    float4 v = ((const float4*)src)[i];
    ushort4 o;
    o.x = f2bf(v.x); o.y = f2bf(v.y); o.z = f2bf(v.z); o.w = f2bf(v.w);
    ((ushort4*)dst)[i] = o;
}

// ---------------- K0b: W_vocab -> bf16 row-major + transposed 32-v blocks ----
__global__ __launch_bounds__(256) void prep_wv(const float* __restrict__ wv,
                                               u16* __restrict__ wvb,
                                               u16* __restrict__ wvt) {
    __shared__ u16 tile[32][776];      // +8 pad
    int tb = blockIdx.x;               // 0..1570
    int tid = threadIdx.x;
    #pragma unroll
    for (int it = 0; it < 12; ++it) {
        int task = tid + 256 * it;     // 3072 = 32 rows * 96 chunks
        int row = task / 96, ch = task % 96;
        int v = tb * 32 + row;
        uint4 pk = {0u, 0u, 0u, 0u};
        if (v < VOCAB) {
            const float* p = wv + (size_t)v * DIM + ch * 8;
            float4 f0 = ((const float4*)p)[0];
            float4 f1 = ((const float4*)p)[1];
            pk.x = (unsigned)f2bf(f0.x) | ((unsigned)f2bf(f0.y) << 16);
            pk.y = (unsigned)f2bf(f0.z) | ((unsigned)f2bf(f0.w) << 16);
            pk.z = (unsigned)f2bf(f1.x) | ((unsigned)f2bf(f1.y) << 16);
            pk.w = (unsigned)f2bf(f1.z) | ((unsigned)f2bf(f1.w) << 16);
        }
        *(uint4*)(wvb + (size_t)v * DIM + ch * 8) = pk;
        *(uint4*)(&tile[row][ch * 8]) = pk;
    }
    __syncthreads();
    #pragma unroll
    for (int it = 0; it < 12; ++it) {
        int task = tid + 256 * it;     // 3072 = 768 d * 4 vchunks
        int d = task >> 2, vc = task & 3;
        u16 t8[8];
        #pragma unroll
        for (int j = 0; j < 8; ++j) t8[j] = tile[vc * 8 + j][d];
        uint4 pk;
        pk.x = (unsigned)t8[0] | ((unsigned)t8[1] << 16);
        pk.y = (unsigned)t8[2] | ((unsigned)t8[3] << 16);
        pk.z = (unsigned)t8[4] | ((unsigned)t8[5] << 16);
        pk.w = (unsigned)t8[6] | ((unsigned)t8[7] << 16);
        *(uint4*)(wvt + (size_t)tb * 24576 + d * 32 + vc * 8) = pk;
    }
}

// ---------------- K1: fused flash over vocab (split-V partials) -------------
// grid 512 = 64 qblocks * 8 splits; 256 threads; dyn LDS 116224 B
__global__ __launch_bounds__(256, 1) void flash_vocab(
    const u16* __restrict__ xb, const u16* __restrict__ wvb,
    const u16* __restrict__ wvt, const float* __restrict__ bvocab,
    float* __restrict__ opart, float* __restrict__ mlpart) {
    extern __shared__ char lds[];
    u16* WS = (u16*)lds;                       // [32][776]  S-phase, d-contig
    u16* WT = (u16*)(lds + 49664);             // [768][40]  PV-phase, v-contig
    u16* PL = (u16*)(lds + 49664 + 61440);     // [4 waves][16][40]

    int bid = blockIdx.x;
    int qb = bid & 63, sv = bid >> 6;
    int tid = threadIdx.x;
    int w = tid >> 6, lane = tid & 63, q = lane >> 4, c = lane & 15;
    int t0 = sv * TILES_PER_SV;
    int t1 = t0 + TILES_PER_SV; if (t1 > NTILES_V) t1 = NTILES_V;
    int vlimit = t1 * 32; if (vlimit > VOCAB) vlimit = VOCAB;
    int rbase = qb * 64 + w * 16;

    // X fragments resident in registers: A[m=lane&15][k=q*8+j], 24 k-steps
    s16x8 xf[24];
    #pragma unroll
    for (int ks = 0; ks < 24; ++ks)
        xf[ks] = *(const s16x8*)(xb + (size_t)(rbase + c) * DIM + ks * 32 + q * 8);

    f32x4 Oa[48];
    #pragma unroll
    for (int n = 0; n < 48; ++n) Oa[n] = (f32x4){0.f, 0.f, 0.f, 0.f};
    float mrow[4], lrow[4];
    #pragma unroll
    for (int j = 0; j < 4; ++j) { mrow[j] = -3.0e38f; lrow[j] = 0.f; }

    for (int t = t0; t < t1; ++t) {
        int vbase = t * 32;
        // stage WS: 32 v-rows x 768 d (bf16, padded stride 776)
        #pragma unroll
        for (int it = 0; it < 12; ++it) {
            int task = tid + 256 * it;
            int row = task / 96, ch = task % 96;
            uint4 pk = *(const uint4*)(wvb + (size_t)(vbase + row) * DIM + ch * 8);
            *(uint4*)(WS + row * 776 + ch * 8) = pk;
        }
        // stage WT: 768 d x 32 v (padded stride 40), linear from blocked copy
        #pragma unroll
        for (int it = 0; it < 12; ++it) {
            int task = tid + 256 * it;
            int d = task >> 2, vc = task & 3;
            uint4 pk = *(const uint4*)(wvt + (size_t)t * 24576 + d * 32 + vc * 8);
            *(uint4*)(WT + d * 40 + vc * 8) = pk;
        }
        __syncthreads();

        // S = X @ Wv^T  (two 16x16 n-tiles)
        f32x4 s0 = (f32x4){0.f,0.f,0.f,0.f}, s1 = (f32x4){0.f,0.f,0.f,0.f};
        #pragma unroll
        for (int ks = 0; ks < 24; ++ks) {
            s16x8 b0 = *(const s16x8*)(WS + c * 776 + ks * 32 + q * 8);
            s16x8 b1 = *(const s16x8*)(WS + (16 + c) * 776 + ks * 32 + q * 8);
            s0 = __builtin_amdgcn_mfma_f32_16x16x32_bf16(xf[ks], b0, s0, 0, 0, 0);
            s1 = __builtin_amdgcn_mfma_f32_16x16x32_bf16(xf[ks], b1, s1, 0, 0, 0);
        }
        int v0 = vbase + c, v1 = vbase + 16 + c;
        float bv0 = (v0 < VOCAB) ? bvocab[v0] : 0.f;
        float bv1 = (v1 < VOCAB) ? bvocab[v1] : 0.f;
        float p0[4], p1[4], alpha[4];
        bool anyscale = false;
        #pragma unroll
        for (int j = 0; j < 4; ++j) {
            float a = s0[j] + bv0; if (v0 >= vlimit) a = -3.0e38f;
            float b = s1[j] + bv1; if (v1 >= vlimit) b = -3.0e38f;
            float mx = fmaxf(a, b);
            mx = fmaxf(mx, __shfl_xor(mx, 1));
            mx = fmaxf(mx, __shfl_xor(mx, 2));
            mx = fmaxf(mx, __shfl_xor(mx, 4));
            mx = fmaxf(mx, __shfl_xor(mx, 8));
            float mn = fmaxf(mrow[j], mx);
            float e0 = __expf(a - mn);
            float e1 = __expf(b - mn);
            p0[j] = e0; p1[j] = e1;
            float sum = e0 + e1;
            sum += __shfl_xor(sum, 1);
            sum += __shfl_xor(sum, 2);
            sum += __shfl_xor(sum, 4);
            sum += __shfl_xor(sum, 8);
            float al = __expf(mrow[j] - mn);
            alpha[j] = al;
            lrow[j] = lrow[j] * al + sum;
            mrow[j] = mn;
            anyscale |= (al != 1.0f);
        }
        // write P (bf16) to wave-private LDS in A-operand-friendly layout
        u16* pl = PL + w * 16 * 40;
        #pragma unroll
        for (int j = 0; j < 4; ++j) {
            pl[(q * 4 + j) * 40 + c]      = f2bf(p0[j]);
            pl[(q * 4 + j) * 40 + 16 + c] = f2bf(p1[j]);
        }
        if (__ballot(anyscale)) {
            #pragma unroll
            for (int n = 0; n < 48; ++n) {
                #pragma unroll
                for (int j = 0; j < 4; ++j) Oa[n][j] *= alpha[j];
            }
        }
        // PV: O[16x768] += P[16x32] @ Wv[32x768]
        s16x8 pa = *(const s16x8*)(pl + c * 40 + q * 8);
        #pragma unroll
        for (int n = 0; n < 48; ++n) {
            s16x8 bw = *(const s16x8*)(WT + (n * 16 + c) * 40 + q * 8);
            Oa[n] = __builtin_amdgcn_mfma_f32_16x16x32_bf16(pa, bw, Oa[n], 0, 0, 0);
        }
        __syncthreads();
    }
    // epilogue: unnormalized O + (m, l) partials
    size_t obase = (size_t)(qb * 8 + sv) * 64 * 768;
    #pragma unroll
    for (int n = 0; n < 48; ++n) {
        #pragma unroll
        for (int j = 0; j < 4; ++j)
            opart[obase + (size_t)(w * 16 + q * 4 + j) * 768 + n * 16 + c] = Oa[n][j];
    }
    if (c == 0) {
        int mbase = (qb * 8 + sv) * 128;
        #pragma unroll
        for (int j = 0; j < 4; ++j) {
            mlpart[mbase + w * 16 + q * 4 + j]      = mrow[j];
            mlpart[mbase + 64 + w * 16 + q * 4 + j] = lrow[j];
        }
    }
}

// ---------------- K2: combine 8 split partials -> h (bf16) ----------------
__global__ __launch_bounds__(256) void combine(const float* __restrict__ opart,
                                               const float* __restrict__ mlpart,
                                               u16* __restrict__ h) {
    int r = blockIdx.x;            // 0..4095
    int qb = r >> 6, rl = r & 63;
    float ms[SV], ls[SV];
    float mstar = -3.0e38f;
    #pragma unroll
    for (int s = 0; s < SV; ++s) {
        ms[s] = mlpart[(qb * 8 + s) * 128 + rl];
        ls[s] = mlpart[(qb * 8 + s) * 128 + 64 + rl];
        mstar = fmaxf(mstar, ms[s]);
    }
    float L = 0.f;
    float sc[SV];
    #pragma unroll
    for (int s = 0; s < SV; ++s) { sc[s] = __expf(ms[s] - mstar); L += ls[s] * sc[s]; }
    float inv = 1.0f / L;
    #pragma unroll
    for (int s = 0; s < SV; ++s) sc[s] *= inv;
    int tid = threadIdx.x;
    #pragma unroll
    for (int jj = 0; jj < 3; ++jj) {
        int d = tid + jj * 256;
        float acc = 0.f;
        #pragma unroll
        for (int s = 0; s < SV; ++s)
            acc += opart[((size_t)(qb * 8 + s) * 64 + rl) * 768 + d] * sc[s];
        h[(size_t)r * 768 + d] = f2bf(acc);
    }
}

// ---------------- K3: out = h @ W_lin^T + b_lin  (128x128 MFMA tile) -------
__global__ __launch_bounds__(256) void final_gemm(const u16* __restrict__ h,
                                                  const u16* __restrict__ wlb,
                                                  const float* __restrict__ blin,
                                                  float* __restrict__ out) {
    __shared__ u16 At[128 * 40];
    __shared__ u16 Bt[128 * 40];
    int mb = blockIdx.x & 31, eb = blockIdx.x >> 5;
    int tid = threadIdx.x;
    int w = tid >> 6, lane = tid & 63, q = lane >> 4, c = lane & 15;
    int wm = w & 1, wn = w >> 1;
    f32x4 acc[4][4];
    #pragma unroll
    for (int i = 0; i < 4; ++i)
        #pragma unroll
        for (int j = 0; j < 4; ++j) acc[i][j] = (f32x4){0.f, 0.f, 0.f, 0.f};

    for (int ko = 0; ko < 24; ++ko) {
        #pragma unroll
        for (int it = 0; it < 2; ++it) {
            int task = tid + 256 * it;     // 512 = 128 rows * 4 chunks
            int row = task >> 2, ch = task & 3;
            *(uint4*)(At + row * 40 + ch * 8) =
                *(const uint4*)(h + (size_t)(mb * 128 + row) * 768 + ko * 32 + ch * 8);
            *(uint4*)(Bt + row * 40 + ch * 8) =
                *(const uint4*)(wlb + (size_t)(eb * 128 + row) * 768 + ko * 32 + ch * 8);
        }
        __syncthreads();
        s16x8 af[4], bf[4];
        #pragma unroll
        for (int i = 0; i < 4; ++i)
            af[i] = *(const s16x8*)(At + (wm * 64 + i * 16 + c) * 40 + q * 8);
        #pragma unroll
        for (int j = 0; j < 4; ++j)
            bf[j] = *(const s16x8*)(Bt + (wn * 64 + j * 16 + c) * 40 + q * 8);
        #pragma unroll
        for (int i = 0; i < 4; ++i)
            #pragma unroll
            for (int j = 0; j < 4; ++j)
                acc[i][j] = __builtin_amdgcn_mfma_f32_16x16x32_bf16(af[i], bf[j], acc[i][j], 0, 0, 0);
        __syncthreads();
    }
    #pragma unroll
    for (int j = 0; j < 4; ++j) {
        int e = eb * 128 + wn * 64 + j * 16 + c;
        float bl = blin[e];
        #pragma unroll
        for (int i = 0; i < 4; ++i) {
            #pragma unroll
            for (int jr = 0; jr < 4; ++jr) {
                int row = mb * 128 + wm * 64 + i * 16 + q * 4 + jr;
                out[(size_t)row * 768 + e] = acc[i][j][jr] + bl;
            }
        }
    }
}

extern "C" void kernel_launch(void* const* d_in, const int* in_sizes, int n_in,
                              void* d_out, int out_size, void* d_ws, size_t ws_size,
                              hipStream_t stream) {
    const float* x  = (const float*)d_in[0];
    const float* Wv = (const float*)d_in[1];
    const float* bv = (const float*)d_in[2];
    const float* Wl = (const float*)d_in[3];
    const float* bl = (const float*)d_in[4];
    float* out = (float*)d_out;
    char* ws = (char*)d_ws;

    u16* xb  = (u16*)(ws + OFF_XB);
    u16* wvb = (u16*)(ws + OFF_WVB);
    u16* wvt = (u16*)(ws + OFF_WVT);
    u16* wlb = (u16*)(ws + OFF_WLB);
    u16* h   = (u16*)(ws + OFF_H);
    float* opart  = (float*)(ws + OFF_OPART);
    float* mlpart = (float*)(ws + OFF_ML);

    // casts
    cast_bf16<<<(M_ROWS * DIM / 4 + 255) / 256, 256, 0, stream>>>(x, xb, M_ROWS * DIM / 4);
    cast_bf16<<<(DIM * DIM / 4 + 255) / 256, 256, 0, stream>>>(Wl, wlb, DIM * DIM / 4);
    prep_wv<<<NTILES_V, 256, 0, stream>>>(Wv, wvb, wvt);

    // fused flash over vocab
    size_t ldsK1 = 49664 + 61440 + 5120;   // 116224 B
    hipFuncSetAttribute(reinterpret_cast<const void*>(flash_vocab),
                        hipFuncAttributeMaxDynamicSharedMemorySize, (int)ldsK1);
    flash_vocab<<<512, 256, ldsK1, stream>>>(xb, wvb, wvt, bv, opart, mlpart);

    // combine splits
    combine<<<M_ROWS, 256, 0, stream>>>(opart, mlpart, h);

    // final linear
    final_gemm<<<192, 256, 0, stream>>>(h, wlb, bl, out);
}

// Round 3
// 3306.603 us; speedup vs baseline: 1.4567x; 1.4567x over previous
//
#include <hip/hip_runtime.h>
#include <hip/hip_bf16.h>
#include <stdint.h>

typedef float f32x4 __attribute__((ext_vector_type(4)));
typedef short s16x8 __attribute__((ext_vector_type(8)));
typedef unsigned short u16;

#define M_ROWS 4096
#define DIM    768
#define VOCAB  50257
#define VPAD   50272           // 1571 * 32
#define NTILES_V 1571
#define SV     8
#define QB     128             // 32 rows per q-block
#define TILES_PER_SV 197       // ceil(1571/8)

// ws layout (bytes)
#define OFF_XB     0ull
#define OFF_WVB    6291456ull          // bf16 [VPAD][768]
#define OFF_WVT    83509248ull         // bf16 blocked [1571][768][32]
#define OFF_WLB    160727040ull        // bf16 [768][768]
#define OFF_H      161906688ull        // bf16 [4096][768]
#define OFF_OPART  168198144ull        // bf16 [1024][32][768]
#define OFF_ML     218529792ull        // f32 [1024][2][32]

__device__ __forceinline__ u16 f2bf(float f) {
    union { float f; unsigned u; } x; x.f = f;
    return (u16)((x.u + 0x7fffu + ((x.u >> 16) & 1u)) >> 16);
}
__device__ __forceinline__ float bf2f(u16 v) {
    union { unsigned u; float f; } x; x.u = ((unsigned)v) << 16;
    return x.f;
}
// WS swizzle: chunk (v in [0,32), dch in [0,96)) -> u16 offset. Injective:
// low-3 bits of dch XORed with v&7 (bijection per v); upper bits untouched.
__device__ __forceinline__ int ws_addr(int v, int dch) {
    return v * 768 + (dch & ~7) * 8 + ((dch ^ v) & 7) * 8;
}

// ---------------- K0a: elementwise f32 -> bf16 cast ----------------
__global__ __launch_bounds__(256) void cast_bf16(const float* __restrict__ src,
                                                 u16* __restrict__ dst, int n4) {
    int i = blockIdx.x * 256 + threadIdx.x;
    if (i >= n4) return;
    float4 v = ((const float4*)src)[i];
    ushort4 o;
    o.x = f2bf(v.x); o.y = f2bf(v.y); o.z = f2bf(v.z); o.w = f2bf(v.w);
    ((ushort4*)dst)[i] = o;
}

// ------- K0b: W_vocab -> bf16 row-major + transposed 32-v blocks (proven R1) -
__global__ __launch_bounds__(256) void prep_wv(const float* __restrict__ wv,
                                               u16* __restrict__ wvb,
                                               u16* __restrict__ wvt) {
    __shared__ u16 tile[32][776];
    int tb = blockIdx.x;               // 0..1570
    int tid = threadIdx.x;
    #pragma unroll
    for (int it = 0; it < 12; ++it) {
        int task = tid + 256 * it;     // 3072 = 32 rows * 96 chunks
        int row = task / 96, ch = task % 96;
        int v = tb * 32 + row;
        uint4 pk = {0u, 0u, 0u, 0u};
        if (v < VOCAB) {
            const float* p = wv + (size_t)v * DIM + ch * 8;
            float4 f0 = ((const float4*)p)[0];
            float4 f1 = ((const float4*)p)[1];
            pk.x = (unsigned)f2bf(f0.x) | ((unsigned)f2bf(f0.y) << 16);
            pk.y = (unsigned)f2bf(f0.z) | ((unsigned)f2bf(f0.w) << 16);
            pk.z = (unsigned)f2bf(f1.x) | ((unsigned)f2bf(f1.y) << 16);
            pk.w = (unsigned)f2bf(f1.z) | ((unsigned)f2bf(f1.w) << 16);
        }
        *(uint4*)(wvb + (size_t)v * DIM + ch * 8) = pk;
        *(uint4*)(&tile[row][ch * 8]) = pk;
    }
    __syncthreads();
    #pragma unroll
    for (int it = 0; it < 12; ++it) {
        int task = tid + 256 * it;     // 3072 = 768 d * 4 vchunks
        int d = task >> 2, vc = task & 3;
        u16 t8[8];
        #pragma unroll
        for (int j = 0; j < 8; ++j) t8[j] = tile[vc * 8 + j][d];
        uint4 pk;
        pk.x = (unsigned)t8[0] | ((unsigned)t8[1] << 16);
        pk.y = (unsigned)t8[2] | ((unsigned)t8[3] << 16);
        pk.z = (unsigned)t8[4] | ((unsigned)t8[5] << 16);
        pk.w = (unsigned)t8[6] | ((unsigned)t8[7] << 16);
        *(uint4*)(wvt + (size_t)tb * 24576 + d * 32 + vc * 8) = pk;
    }
}

// ---------------- K1: fused flash over vocab (split-V partials) -------------
// grid 1024 = 128 qblocks * 8 sv (sv XCD-affine); 256 thr; dyn LDS 74240 B
__global__ __launch_bounds__(256, 2) void flash_vocab(
    const u16* __restrict__ xb, const u16* __restrict__ wvb,
    const u16* __restrict__ wvt, const float* __restrict__ bvocab,
    u16* __restrict__ opart, float* __restrict__ mlpart) {
    extern __shared__ char lds[];
    u16* WS   = (u16*)lds;                   // 24576 u16 swizzled (49152 B)
    u16* WT0  = WS + 24576;                  // [128][40] u16 (10240 B)
    u16* WT1  = WT0 + 5120;                  // [128][40] u16
    float* SP = (float*)(lds + 69632);       // [32][36] f32 (4608 B)
    u16* PLo  = (u16*)SP;                    // P overlay: row stride 72 u16
    // alpha overlay: SP[row*36 + 35]

    int bid = blockIdx.x;
    int sv = bid & 7, qb = bid >> 3;
    int tid = threadIdx.x;
    int w = tid >> 6, lane = tid & 63, q = lane >> 4, c = lane & 15;
    int rt = w & 1, nt = w >> 1;             // S job: row-tile, n-tile
    int srow = tid >> 3, scg = tid & 7;      // softmax: row owner, col group
    int t0 = sv * TILES_PER_SV;
    int t1 = t0 + TILES_PER_SV; if (t1 > NTILES_V) t1 = NTILES_V;
    int vlimit = t1 * 32; if (vlimit > VOCAB) vlimit = VOCAB;

    // X fragments for this wave's S row-tile: A[m=c][k=q*8+j]
    s16x8 xf[24];
    int xrow = qb * 32 + rt * 16 + c;
    #pragma unroll
    for (int ks = 0; ks < 24; ++ks)
        xf[ks] = *(const s16x8*)(xb + (size_t)xrow * DIM + ks * 32 + q * 8);

    // O accumulators: wave owns d-tiles {tau : tau % 4 == w}, both row-tiles.
    // acc[rt2][2*r + s] <-> d-tile tau = 8*r + w + 4*s
    f32x4 acc[2][12];
    #pragma unroll
    for (int a = 0; a < 2; ++a)
        #pragma unroll
        for (int i = 0; i < 12; ++i) acc[a][i] = (f32x4){0.f, 0.f, 0.f, 0.f};
    float m_s = -3.0e38f, l_s = 0.f;         // per softmax-thread row state

    for (int t = t0; t < t1; ++t) {
        int vbase = t * 32;
        // ---- phase A: stage WS (swizzled) + WT buf0 (d-tiles 0..7) ----
        #pragma unroll 4
        for (int it = 0; it < 12; ++it) {
            int task = it * 256 + tid;
            int v = task / 96, dch = task % 96;
            uint4 pk = *(const uint4*)(wvb + (size_t)(vbase + v) * DIM + dch * 8);
            *(uint4*)(WS + ws_addr(v, dch)) = pk;
        }
        #pragma unroll
        for (int it = 0; it < 2; ++it) {
            int task = it * 256 + tid;
            int ld = task >> 2, vc = task & 3;
            uint4 pk = *(const uint4*)(wvt + (size_t)t * 24576 + ld * 32 + vc * 8);
            *(uint4*)(WT0 + ld * 40 + vc * 8) = pk;
        }
        __syncthreads();

        // ---- S: 16 rows x 16 cols per wave, two interleaved accumulators ----
        f32x4 sa = (f32x4){0.f,0.f,0.f,0.f}, sb = (f32x4){0.f,0.f,0.f,0.f};
        #pragma unroll
        for (int ks = 0; ks < 24; ks += 2) {
            s16x8 b0 = *(const s16x8*)(WS + ws_addr(nt * 16 + c, ks * 4 + q));
            s16x8 b1 = *(const s16x8*)(WS + ws_addr(nt * 16 + c, ks * 4 + 4 + q));
            sa = __builtin_amdgcn_mfma_f32_16x16x32_bf16(xf[ks], b0, sa, 0, 0, 0);
            sb = __builtin_amdgcn_mfma_f32_16x16x32_bf16(xf[ks + 1], b1, sb, 0, 0, 0);
        }
        #pragma unroll
        for (int j = 0; j < 4; ++j)
            SP[(rt * 16 + q * 4 + j) * 36 + nt * 16 + c] = sa[j] + sb[j];
        __syncthreads();

        // ---- softmax: thread owns (srow, 4 cols) ----
        float z[4];
        {
            float2 lo = *(const float2*)(SP + srow * 36 + 2 * scg);
            float2 hi = *(const float2*)(SP + srow * 36 + 16 + 2 * scg);
            z[0] = lo.x; z[1] = lo.y; z[2] = hi.x; z[3] = hi.y;
        }
        __syncthreads();     // all SP reads done before P/alpha overlay writes
        int vc0 = vbase + 2 * scg, vc2 = vbase + 16 + 2 * scg;
        int vid[4] = {vc0, vc0 + 1, vc2, vc2 + 1};
        #pragma unroll
        for (int j = 0; j < 4; ++j) {
            float bv = (vid[j] < VOCAB) ? bvocab[vid[j]] : 0.f;
            z[j] = (vid[j] < vlimit) ? (z[j] + bv) : -3.0e38f;
        }
        float mx = fmaxf(fmaxf(z[0], z[1]), fmaxf(z[2], z[3]));
        mx = fmaxf(mx, __shfl_xor(mx, 1));
        mx = fmaxf(mx, __shfl_xor(mx, 2));
        mx = fmaxf(mx, __shfl_xor(mx, 4));
        float mn = fmaxf(m_s, mx);
        float e[4];
        #pragma unroll
        for (int j = 0; j < 4; ++j) e[j] = __expf(z[j] - mn);
        float sum = e[0] + e[1] + e[2] + e[3];
        sum += __shfl_xor(sum, 1);
        sum += __shfl_xor(sum, 2);
        sum += __shfl_xor(sum, 4);
        float alpha = __expf(m_s - mn);
        l_s = l_s * alpha + sum;
        m_s = mn;
        *(unsigned*)(PLo + srow * 72 + 2 * scg) =
            (unsigned)f2bf(e[0]) | ((unsigned)f2bf(e[1]) << 16);
        *(unsigned*)(PLo + srow * 72 + 16 + 2 * scg) =
            (unsigned)f2bf(e[2]) | ((unsigned)f2bf(e[3]) << 16);
        if (scg == 0) SP[srow * 36 + 35] = alpha;
        __syncthreads();     // P + alpha visible

        // ---- load P A-frags + alpha, rescale acc ----
        s16x8 pa0 = *(const s16x8*)(PLo + c * 72 + q * 8);
        s16x8 pa1 = *(const s16x8*)(PLo + (16 + c) * 72 + q * 8);
        float al[2][4];
        bool need = false;
        #pragma unroll
        for (int a = 0; a < 2; ++a)
            #pragma unroll
            for (int j = 0; j < 4; ++j) {
                al[a][j] = SP[(a * 16 + q * 4 + j) * 36 + 35];
                need |= (al[a][j] != 1.0f);
            }
        if (__ballot(need)) {
            #pragma unroll
            for (int a = 0; a < 2; ++a)
                #pragma unroll
                for (int i = 0; i < 12; ++i)
                    #pragma unroll
                    for (int j = 0; j < 4; ++j) acc[a][i][j] *= al[a][j];
        }

        // ---- PV: 6 rounds of 8 d-tiles, ping-pong prefetch of WT ----
        #pragma unroll
        for (int r = 0; r < 6; ++r) {
            u16* cur = (r & 1) ? WT1 : WT0;
            u16* nxt = (r & 1) ? WT0 : WT1;
            uint4 st0, st1;
            if (r < 5) {
                int task0 = tid, task1 = 256 + tid;
                int ld0 = task0 >> 2, vc_0 = task0 & 3;
                int ld1 = task1 >> 2, vc_1 = task1 & 3;
                st0 = *(const uint4*)(wvt + (size_t)t * 24576 + ((r + 1) * 128 + ld0) * 32 + vc_0 * 8);
                st1 = *(const uint4*)(wvt + (size_t)t * 24576 + ((r + 1) * 128 + ld1) * 32 + vc_1 * 8);
            }
            #pragma unroll
            for (int s2 = 0; s2 < 2; ++s2) {
                s16x8 bw = *(const s16x8*)(cur + ((w + 4 * s2) * 16 + c) * 40 + q * 8);
                acc[0][2 * r + s2] = __builtin_amdgcn_mfma_f32_16x16x32_bf16(pa0, bw, acc[0][2 * r + s2], 0, 0, 0);
                acc[1][2 * r + s2] = __builtin_amdgcn_mfma_f32_16x16x32_bf16(pa1, bw, acc[1][2 * r + s2], 0, 0, 0);
            }
            if (r < 5) {
                int task0 = tid, task1 = 256 + tid;
                *(uint4*)(nxt + (task0 >> 2) * 40 + (task0 & 3) * 8) = st0;
                *(uint4*)(nxt + (task1 >> 2) * 40 + (task1 & 3) * 8) = st1;
            }
            __syncthreads();
        }
    }
    // ---- epilogue: unnormalized O (bf16) + (m, l) ----
    int ob = qb * 8 + sv;
    size_t obase = (size_t)ob * 32 * 768;
    #pragma unroll
    for (int a = 0; a < 2; ++a)
        #pragma unroll
        for (int r = 0; r < 6; ++r)
            #pragma unroll
            for (int s2 = 0; s2 < 2; ++s2) {
                int d = (8 * r + w + 4 * s2) * 16 + c;
                #pragma unroll
                for (int j = 0; j < 4; ++j) {
                    int row = a * 16 + q * 4 + j;
                    opart[obase + (size_t)row * 768 + d] = f2bf(acc[a][2 * r + s2][j]);
                }
            }
    if (scg == 0) {
        mlpart[ob * 64 + srow]      = m_s;
        mlpart[ob * 64 + 32 + srow] = l_s;
    }
}

// ---------------- K2: combine 8 split partials -> h (bf16) ----------------
__global__ __launch_bounds__(256) void combine(const u16* __restrict__ opart,
                                               const float* __restrict__ mlpart,
                                               u16* __restrict__ h) {
    int r = blockIdx.x;            // 0..4095
    int qb = r >> 5, rl = r & 31;
    float ms[SV], ls[SV];
    float mstar = -3.0e38f;
    #pragma unroll
    for (int s = 0; s < SV; ++s) {
        ms[s] = mlpart[(qb * 8 + s) * 64 + rl];
        ls[s] = mlpart[(qb * 8 + s) * 64 + 32 + rl];
        mstar = fmaxf(mstar, ms[s]);
    }
    float L = 0.f;
    float sc[SV];
    #pragma unroll
    for (int s = 0; s < SV; ++s) { sc[s] = __expf(ms[s] - mstar); L += ls[s] * sc[s]; }
    float inv = 1.0f / L;
    #pragma unroll
    for (int s = 0; s < SV; ++s) sc[s] *= inv;
    int tid = threadIdx.x;
    #pragma unroll
    for (int jj = 0; jj < 3; ++jj) {
        int d = tid + jj * 256;
        float acc = 0.f;
        #pragma unroll
        for (int s = 0; s < SV; ++s)
            acc += bf2f(opart[((size_t)(qb * 8 + s) * 32 + rl) * 768 + d]) * sc[s];
        h[(size_t)r * 768 + d] = f2bf(acc);
    }
}

// ---------------- K3: out = h @ W_lin^T + b_lin  (128x128 MFMA tile) -------
__global__ __launch_bounds__(256) void final_gemm(const u16* __restrict__ h,
                                                  const u16* __restrict__ wlb,
                                                  const float* __restrict__ blin,
                                                  float* __restrict__ out) {
    __shared__ u16 At[128 * 40];
    __shared__ u16 Bt[128 * 40];
    int mb = blockIdx.x & 31, eb = blockIdx.x >> 5;
    int tid = threadIdx.x;
    int w = tid >> 6, lane = tid & 63, q = lane >> 4, c = lane & 15;
    int wm = w & 1, wn = w >> 1;
    f32x4 acc[4][4];
    #pragma unroll
    for (int i = 0; i < 4; ++i)
        #pragma unroll
        for (int j = 0; j < 4; ++j) acc[i][j] = (f32x4){0.f, 0.f, 0.f, 0.f};

    for (int ko = 0; ko < 24; ++ko) {
        #pragma unroll
        for (int it = 0; it < 2; ++it) {
            int task = tid + 256 * it;     // 512 = 128 rows * 4 chunks
            int row = task >> 2, ch = task & 3;
            *(uint4*)(At + row * 40 + ch * 8) =
                *(const uint4*)(h + (size_t)(mb * 128 + row) * 768 + ko * 32 + ch * 8);
            *(uint4*)(Bt + row * 40 + ch * 8) =
                *(const uint4*)(wlb + (size_t)(eb * 128 + row) * 768 + ko * 32 + ch * 8);
        }
        __syncthreads();
        s16x8 af[4], bf[4];
        #pragma unroll
        for (int i = 0; i < 4; ++i)
            af[i] = *(const s16x8*)(At + (wm * 64 + i * 16 + c) * 40 + q * 8);
        #pragma unroll
        for (int j = 0; j < 4; ++j)
            bf[j] = *(const s16x8*)(Bt + (wn * 64 + j * 16 + c) * 40 + q * 8);
        #pragma unroll
        for (int i = 0; i < 4; ++i)
            #pragma unroll
            for (int j = 0; j < 4; ++j)
                acc[i][j] = __builtin_amdgcn_mfma_f32_16x16x32_bf16(af[i], bf[j], acc[i][j], 0, 0, 0);
        __syncthreads();
    }
    #pragma unroll
    for (int j = 0; j < 4; ++j) {
        int e = eb * 128 + wn * 64 + j * 16 + c;
        float bl = blin[e];
        #pragma unroll
        for (int i = 0; i < 4; ++i) {
            #pragma unroll
            for (int jr = 0; jr < 4; ++jr) {
                int row = mb * 128 + wm * 64 + i * 16 + q * 4 + jr;
                out[(size_t)row * 768 + e] = acc[i][j][jr] + bl;
            }
        }
    }
}

extern "C" void kernel_launch(void* const* d_in, const int* in_sizes, int n_in,
                              void* d_out, int out_size, void* d_ws, size_t ws_size,
                              hipStream_t stream) {
    const float* x  = (const float*)d_in[0];
    const float* Wv = (const float*)d_in[1];
    const float* bv = (const float*)d_in[2];
    const float* Wl = (const float*)d_in[3];
    const float* bl = (const float*)d_in[4];
    float* out = (float*)d_out;
    char* ws = (char*)d_ws;

    u16* xb  = (u16*)(ws + OFF_XB);
    u16* wvb = (u16*)(ws + OFF_WVB);
    u16* wvt = (u16*)(ws + OFF_WVT);
    u16* wlb = (u16*)(ws + OFF_WLB);
    u16* h   = (u16*)(ws + OFF_H);
    u16* opart    = (u16*)(ws + OFF_OPART);
    float* mlpart = (float*)(ws + OFF_ML);

    // casts + W_vocab prep
    cast_bf16<<<(M_ROWS * DIM / 4 + 255) / 256, 256, 0, stream>>>(x, xb, M_ROWS * DIM / 4);
    cast_bf16<<<(DIM * DIM / 4 + 255) / 256, 256, 0, stream>>>(Wl, wlb, DIM * DIM / 4);
    prep_wv<<<NTILES_V, 256, 0, stream>>>(Wv, wvb, wvt);

    // fused flash over vocab
    size_t ldsK1 = 74240;
    hipFuncSetAttribute(reinterpret_cast<const void*>(flash_vocab),
                        hipFuncAttributeMaxDynamicSharedMemorySize, (int)ldsK1);
    flash_vocab<<<QB * SV, 256, ldsK1, stream>>>(xb, wvb, wvt, bv, opart, mlpart);

    // combine splits
    combine<<<M_ROWS, 256, 0, stream>>>(opart, mlpart, h);

    // final linear
    final_gemm<<<192, 256, 0, stream>>>(h, wlb, bl, out);
}

// Round 4
// 3038.169 us; speedup vs baseline: 1.5854x; 1.0884x over previous
//
#include <hip/hip_runtime.h>
#include <hip/hip_bf16.h>
#include <stdint.h>

typedef float f32x4 __attribute__((ext_vector_type(4)));
typedef short s16x8 __attribute__((ext_vector_type(8)));
typedef unsigned short u16;

#define M_ROWS 4096
#define DIM    768
#define VOCAB  50257
#define VPAD64 50304           // 786 * 64
#define NT32   1572            // 32-col blocks in wvt (incl. 1 zero pad blk)
#define NT64   786             // 64-col tiles
#define SV     4
#define QB     128             // 32 rows per q-block

// ws layout (bytes)
#define OFF_XB     0ull
#define OFF_WVB    6291456ull          // bf16 [50304][768]
#define OFF_WVT    83558400ull         // bf16 blocked [1572][768][32]
#define OFF_WLB    160825344ull        // bf16 [768][768]
#define OFF_H      162004992ull        // bf16 [4096][768]
#define OFF_OPART  168296448ull        // bf16 [512][32][768]
#define OFF_ML     193462272ull        // f32 [512][2][32]

__device__ __forceinline__ u16 f2bf(float f) {
    union { float f; unsigned u; } x; x.f = f;
    return (u16)((x.u + 0x7fffu + ((x.u >> 16) & 1u)) >> 16);
}
__device__ __forceinline__ float bf2f(u16 v) {
    union { unsigned u; float f; } x; x.u = ((unsigned)v) << 16;
    return x.f;
}

// ---------------- K0a: elementwise f32 -> bf16 cast ----------------
__global__ __launch_bounds__(256) void cast_bf16(const float* __restrict__ src,
                                                 u16* __restrict__ dst, int n4) {
    int i = blockIdx.x * 256 + threadIdx.x;
    if (i >= n4) return;
    float4 v = ((const float4*)src)[i];
    ushort4 o;
    o.x = f2bf(v.x); o.y = f2bf(v.y); o.z = f2bf(v.z); o.w = f2bf(v.w);
    ((ushort4*)dst)[i] = o;
}

// ------- K0b: W_vocab -> bf16 row-major + transposed 32-v blocks ------------
__global__ __launch_bounds__(256) void prep_wv(const float* __restrict__ wv,
                                               u16* __restrict__ wvb,
                                               u16* __restrict__ wvt) {
    __shared__ u16 tile[32][776];
    int tb = blockIdx.x;               // 0..1571
    int tid = threadIdx.x;
    #pragma unroll
    for (int it = 0; it < 12; ++it) {
        int task = tid + 256 * it;     // 3072 = 32 rows * 96 chunks
        int row = task / 96, ch = task % 96;
        int v = tb * 32 + row;
        uint4 pk = {0u, 0u, 0u, 0u};
        if (v < VOCAB) {
            const float* p = wv + (size_t)v * DIM + ch * 8;
            float4 f0 = ((const float4*)p)[0];
            float4 f1 = ((const float4*)p)[1];
            pk.x = (unsigned)f2bf(f0.x) | ((unsigned)f2bf(f0.y) << 16);
            pk.y = (unsigned)f2bf(f0.z) | ((unsigned)f2bf(f0.w) << 16);
            pk.z = (unsigned)f2bf(f1.x) | ((unsigned)f2bf(f1.y) << 16);
            pk.w = (unsigned)f2bf(f1.z) | ((unsigned)f2bf(f1.w) << 16);
        }
        *(uint4*)(wvb + (size_t)v * DIM + ch * 8) = pk;
        *(uint4*)(&tile[row][ch * 8]) = pk;
    }
    __syncthreads();
    #pragma unroll
    for (int it = 0; it < 12; ++it) {
        int task = tid + 256 * it;     // 3072 = 768 d * 4 vchunks
        int d = task >> 2, vc = task & 3;
        u16 t8[8];
        #pragma unroll
        for (int j = 0; j < 8; ++j) t8[j] = tile[vc * 8 + j][d];
        uint4 pk;
        pk.x = (unsigned)t8[0] | ((unsigned)t8[1] << 16);
        pk.y = (unsigned)t8[2] | ((unsigned)t8[3] << 16);
        pk.z = (unsigned)t8[4] | ((unsigned)t8[5] << 16);
        pk.w = (unsigned)t8[6] | ((unsigned)t8[7] << 16);
        *(uint4*)(wvt + (size_t)tb * 24576 + d * 32 + vc * 8) = pk;
    }
}

// ---------------- K1: fused flash over vocab, B-operands direct from L2 -----
// grid 512 = 128 qblocks * 4 sv; 256 thr; static LDS ~26.9 KB; 2 barriers/tile
__global__ __launch_bounds__(256, 2) void flash_vocab(
    const u16* __restrict__ xb, const u16* __restrict__ wvb,
    const u16* __restrict__ wvt, const float* __restrict__ bvocab,
    u16* __restrict__ opart, float* __restrict__ mlpart) {
    __shared__ float SP[2][32 * 68];   // S scores f32, row stride 68
    __shared__ u16  PL[2][32 * 72];    // P bf16, row stride 72
    __shared__ float AL[2][32];        // alpha per row

    int bid = blockIdx.x;
    int sv = bid & 3, qb = bid >> 2;
    int tid = threadIdx.x;
    int w = tid >> 6, lane = tid & 63, q = lane >> 4, c = lane & 15;
    int rt = w & 1;                    // S row-tile
    int sh16 = (w >> 1) * 32;          // S col-subtile base (two 16-col tiles)
    int srow = tid >> 3, scg = tid & 7;
    int t0 = (sv * NT64) / SV, t1 = ((sv + 1) * NT64) / SV;
    int vlimit = t1 * 64; if (vlimit > VOCAB) vlimit = VOCAB;

    // X fragments resident: A[m=c][k=q*8+j], 24 k-steps for this wave's rows
    s16x8 xf[24];
    int xrow = qb * 32 + rt * 16 + c;
    #pragma unroll
    for (int ks = 0; ks < 24; ++ks)
        xf[ks] = *(const s16x8*)(xb + (size_t)xrow * DIM + ks * 32 + q * 8);

    // O accumulators: wave owns d-tiles dt = w*12 + i  (d = w*192 + i*16 + c)
    f32x4 acc[2][12];
    #pragma unroll
    for (int a = 0; a < 2; ++a)
        #pragma unroll
        for (int i = 0; i < 12; ++i) acc[a][i] = (f32x4){0.f, 0.f, 0.f, 0.f};
    float m_s = -3.0e38f, l_s = 0.f;

    for (int t = t0; t < t1; ++t) {
        int vbase = t * 64;
        int p = t & 1;
        // ---- S-phase: B-frags straight from wvb (L2-resident) ----
        const s16x8* bp0 = (const s16x8*)(wvb + (size_t)(vbase + sh16 + c) * DIM + q * 8);
        const s16x8* bp1 = (const s16x8*)(wvb + (size_t)(vbase + sh16 + 16 + c) * DIM + q * 8);
        f32x4 s0 = (f32x4){0.f,0.f,0.f,0.f}, s1 = (f32x4){0.f,0.f,0.f,0.f};
        #pragma unroll
        for (int ks = 0; ks < 24; ++ks) {
            s16x8 b0 = bp0[ks * 4];
            s16x8 b1 = bp1[ks * 4];
            s0 = __builtin_amdgcn_mfma_f32_16x16x32_bf16(xf[ks], b0, s0, 0, 0, 0);
            s1 = __builtin_amdgcn_mfma_f32_16x16x32_bf16(xf[ks], b1, s1, 0, 0, 0);
        }
        #pragma unroll
        for (int j = 0; j < 4; ++j) {
            SP[p][(rt * 16 + q * 4 + j) * 68 + sh16 + c]      = s0[j];
            SP[p][(rt * 16 + q * 4 + j) * 68 + sh16 + 16 + c] = s1[j];
        }
        __syncthreads();

        // ---- softmax: thread (srow, scg) owns 8 cols ----
        float z[8];
        {
            float4 za = *(const float4*)&SP[p][srow * 68 + scg * 8];
            float4 zb = *(const float4*)&SP[p][srow * 68 + scg * 8 + 4];
            z[0]=za.x; z[1]=za.y; z[2]=za.z; z[3]=za.w;
            z[4]=zb.x; z[5]=zb.y; z[6]=zb.z; z[7]=zb.w;
        }
        int vc0 = vbase + scg * 8;
        if (vc0 + 8 <= VOCAB) {
            float4 ba = *(const float4*)(bvocab + vc0);
            float4 bb = *(const float4*)(bvocab + vc0 + 4);
            z[0]+=ba.x; z[1]+=ba.y; z[2]+=ba.z; z[3]+=ba.w;
            z[4]+=bb.x; z[5]+=bb.y; z[6]+=bb.z; z[7]+=bb.w;
            #pragma unroll
            for (int jj = 0; jj < 8; ++jj)
                if (vc0 + jj >= vlimit) z[jj] = -3.0e38f;
        } else {
            #pragma unroll
            for (int jj = 0; jj < 8; ++jj) {
                if (vc0 + jj < vlimit) z[jj] += bvocab[vc0 + jj];
                else z[jj] = -3.0e38f;
            }
        }
        float mx = z[0];
        #pragma unroll
        for (int jj = 1; jj < 8; ++jj) mx = fmaxf(mx, z[jj]);
        mx = fmaxf(mx, __shfl_xor(mx, 1));
        mx = fmaxf(mx, __shfl_xor(mx, 2));
        mx = fmaxf(mx, __shfl_xor(mx, 4));
        float mn = fmaxf(m_s, mx);
        float e[8], sum = 0.f;
        #pragma unroll
        for (int jj = 0; jj < 8; ++jj) { e[jj] = __expf(z[jj] - mn); sum += e[jj]; }
        sum += __shfl_xor(sum, 1);
        sum += __shfl_xor(sum, 2);
        sum += __shfl_xor(sum, 4);
        float alpha = __expf(m_s - mn);
        l_s = l_s * alpha + sum;
        m_s = mn;
        uint4 pk;
        pk.x = (unsigned)f2bf(e[0]) | ((unsigned)f2bf(e[1]) << 16);
        pk.y = (unsigned)f2bf(e[2]) | ((unsigned)f2bf(e[3]) << 16);
        pk.z = (unsigned)f2bf(e[4]) | ((unsigned)f2bf(e[5]) << 16);
        pk.w = (unsigned)f2bf(e[6]) | ((unsigned)f2bf(e[7]) << 16);
        *(uint4*)&PL[p][srow * 72 + scg * 8] = pk;
        if (scg == 0) AL[p][srow] = alpha;
        __syncthreads();

        // ---- PV: P A-frags from LDS, B-frags straight from wvt ----
        s16x8 pf[2][2];
        #pragma unroll
        for (int a = 0; a < 2; ++a)
            #pragma unroll
            for (int kh = 0; kh < 2; ++kh)
                pf[a][kh] = *(const s16x8*)&PL[p][(a * 16 + c) * 72 + kh * 32 + q * 8];
        f32x4 al0 = *(const f32x4*)&AL[p][q * 4];
        f32x4 al1 = *(const f32x4*)&AL[p][16 + q * 4];
        bool need = false;
        #pragma unroll
        for (int j = 0; j < 4; ++j) need |= (al0[j] != 1.0f) | (al1[j] != 1.0f);
        if (__ballot(need)) {
            #pragma unroll
            for (int i = 0; i < 12; ++i)
                #pragma unroll
                for (int j = 0; j < 4; ++j) {
                    acc[0][i][j] *= al0[j];
                    acc[1][i][j] *= al1[j];
                }
        }
        const u16* wb0 = wvt + (size_t)(2 * t) * 24576 + (size_t)(w * 192 + c) * 32 + q * 8;
        #pragma unroll
        for (int i = 0; i < 12; ++i) {
            s16x8 bw0 = *(const s16x8*)(wb0 + i * 512);
            s16x8 bw1 = *(const s16x8*)(wb0 + 24576 + i * 512);
            acc[0][i] = __builtin_amdgcn_mfma_f32_16x16x32_bf16(pf[0][0], bw0, acc[0][i], 0, 0, 0);
            acc[1][i] = __builtin_amdgcn_mfma_f32_16x16x32_bf16(pf[1][0], bw0, acc[1][i], 0, 0, 0);
            acc[0][i] = __builtin_amdgcn_mfma_f32_16x16x32_bf16(pf[0][1], bw1, acc[0][i], 0, 0, 0);
            acc[1][i] = __builtin_amdgcn_mfma_f32_16x16x32_bf16(pf[1][1], bw1, acc[1][i], 0, 0, 0);
        }
    }
    // ---- epilogue: unnormalized O (bf16) + (m, l) ----
    int ob = qb * SV + sv;
    size_t obase = (size_t)ob * 32 * 768;
    #pragma unroll
    for (int a = 0; a < 2; ++a)
        #pragma unroll
        for (int i = 0; i < 12; ++i) {
            int d = w * 192 + i * 16 + c;
            #pragma unroll
            for (int j = 0; j < 4; ++j) {
                int row = a * 16 + q * 4 + j;
                opart[obase + (size_t)row * 768 + d] = f2bf(acc[a][i][j]);
            }
        }
    if (scg == 0) {
        mlpart[ob * 64 + srow]      = m_s;
        mlpart[ob * 64 + 32 + srow] = l_s;
    }
}

// ---------------- K2: combine 4 split partials -> h (bf16) ----------------
__global__ __launch_bounds__(256) void combine(const u16* __restrict__ opart,
                                               const float* __restrict__ mlpart,
                                               u16* __restrict__ h) {
    int r = blockIdx.x;            // 0..4095
    int qb = r >> 5, rl = r & 31;
    float ms[SV], ls[SV];
    float mstar = -3.0e38f;
    #pragma unroll
    for (int s = 0; s < SV; ++s) {
        ms[s] = mlpart[(qb * SV + s) * 64 + rl];
        ls[s] = mlpart[(qb * SV + s) * 64 + 32 + rl];
        mstar = fmaxf(mstar, ms[s]);
    }
    float L = 0.f;
    float sc[SV];
    #pragma unroll
    for (int s = 0; s < SV; ++s) { sc[s] = __expf(ms[s] - mstar); L += ls[s] * sc[s]; }
    float inv = 1.0f / L;
    #pragma unroll
    for (int s = 0; s < SV; ++s) sc[s] *= inv;
    int tid = threadIdx.x;
    #pragma unroll
    for (int jj = 0; jj < 3; ++jj) {
        int d = tid + jj * 256;
        float acc = 0.f;
        #pragma unroll
        for (int s = 0; s < SV; ++s)
            acc += bf2f(opart[((size_t)(qb * SV + s) * 32 + rl) * 768 + d]) * sc[s];
        h[(size_t)r * 768 + d] = f2bf(acc);
    }
}

// ---------------- K3: out = h @ W_lin^T + b_lin  (128x128 MFMA tile) -------
__global__ __launch_bounds__(256) void final_gemm(const u16* __restrict__ h,
                                                  const u16* __restrict__ wlb,
                                                  const float* __restrict__ blin,
                                                  float* __restrict__ out) {
    __shared__ u16 At[128 * 40];
    __shared__ u16 Bt[128 * 40];
    int mb = blockIdx.x & 31, eb = blockIdx.x >> 5;
    int tid = threadIdx.x;
    int w = tid >> 6, lane = tid & 63, q = lane >> 4, c = lane & 15;
    int wm = w & 1, wn = w >> 1;
    f32x4 acc[4][4];
    #pragma unroll
    for (int i = 0; i < 4; ++i)
        #pragma unroll
        for (int j = 0; j < 4; ++j) acc[i][j] = (f32x4){0.f, 0.f, 0.f, 0.f};

    for (int ko = 0; ko < 24; ++ko) {
        #pragma unroll
        for (int it = 0; it < 2; ++it) {
            int task = tid + 256 * it;     // 512 = 128 rows * 4 chunks
            int row = task >> 2, ch = task & 3;
            *(uint4*)(At + row * 40 + ch * 8) =
                *(const uint4*)(h + (size_t)(mb * 128 + row) * 768 + ko * 32 + ch * 8);
            *(uint4*)(Bt + row * 40 + ch * 8) =
                *(const uint4*)(wlb + (size_t)(eb * 128 + row) * 768 + ko * 32 + ch * 8);
        }
        __syncthreads();
        s16x8 af[4], bf[4];
        #pragma unroll
        for (int i = 0; i < 4; ++i)
            af[i] = *(const s16x8*)(At + (wm * 64 + i * 16 + c) * 40 + q * 8);
        #pragma unroll
        for (int j = 0; j < 4; ++j)
            bf[j] = *(const s16x8*)(Bt + (wn * 64 + j * 16 + c) * 40 + q * 8);
        #pragma unroll
        for (int i = 0; i < 4; ++i)
            #pragma unroll
            for (int j = 0; j < 4; ++j)
                acc[i][j] = __builtin_amdgcn_mfma_f32_16x16x32_bf16(af[i], bf[j], acc[i][j], 0, 0, 0);
        __syncthreads();
    }
    #pragma unroll
    for (int j = 0; j < 4; ++j) {
        int e = eb * 128 + wn * 64 + j * 16 + c;
        float bl = blin[e];
        #pragma unroll
        for (int i = 0; i < 4; ++i) {
            #pragma unroll
            for (int jr = 0; jr < 4; ++jr) {
                int row = mb * 128 + wm * 64 + i * 16 + q * 4 + jr;
                out[(size_t)row * 768 + e] = acc[i][j][jr] + bl;
            }
        }
    }
}

extern "C" void kernel_launch(void* const* d_in, const int* in_sizes, int n_in,
                              void* d_out, int out_size, void* d_ws, size_t ws_size,
                              hipStream_t stream) {
    const float* x  = (const float*)d_in[0];
    const float* Wv = (const float*)d_in[1];
    const float* bv = (const float*)d_in[2];
    const float* Wl = (const float*)d_in[3];
    const float* bl = (const float*)d_in[4];
    float* out = (float*)d_out;
    char* ws = (char*)d_ws;

    u16* xb  = (u16*)(ws + OFF_XB);
    u16* wvb = (u16*)(ws + OFF_WVB);
    u16* wvt = (u16*)(ws + OFF_WVT);
    u16* wlb = (u16*)(ws + OFF_WLB);
    u16* h   = (u16*)(ws + OFF_H);
    u16* opart    = (u16*)(ws + OFF_OPART);
    float* mlpart = (float*)(ws + OFF_ML);

    // casts + W_vocab prep
    cast_bf16<<<(M_ROWS * DIM / 4 + 255) / 256, 256, 0, stream>>>(x, xb, M_ROWS * DIM / 4);
    cast_bf16<<<(DIM * DIM / 4 + 255) / 256, 256, 0, stream>>>(Wl, wlb, DIM * DIM / 4);
    prep_wv<<<NT32, 256, 0, stream>>>(Wv, wvb, wvt);

    // fused flash over vocab
    flash_vocab<<<QB * SV, 256, 0, stream>>>(xb, wvb, wvt, bv, opart, mlpart);

    // combine splits
    combine<<<M_ROWS, 256, 0, stream>>>(opart, mlpart, h);

    // final linear
    final_gemm<<<192, 256, 0, stream>>>(h, wlb, bl, out);
}

// Round 5
// 1764.213 us; speedup vs baseline: 2.7302x; 1.7221x over previous
//
#include <hip/hip_runtime.h>
#include <hip/hip_bf16.h>
#include <stdint.h>

typedef float f32x4 __attribute__((ext_vector_type(4)));
typedef short s16x8 __attribute__((ext_vector_type(8)));
typedef unsigned short u16;

#define M_ROWS 4096
#define DIM    768
#define VOCAB  50257
#define VPAD   50304           // 393 * 128
#define SCALE_PITCH 158        // max 64-col tiles per chunk (79*2)

// ws layout (bytes) — total 222,396,416 (< 269 MB proven-safe)
#define OFF_XB     0ull                // bf16 [4096][768]
#define OFF_WLB    6291456ull          // bf16 [768][768]
#define OFF_WVB    7471104ull          // bf16 [50304][768]
#define OFF_WVTC   84738048ull         // bf16 [<=316][768][32] per-chunk transposed
#define OFF_P      100270080ull        // bf16 [4096][<=10112] chunk P
#define OFF_AUX    183107584ull        // float2 [4096][158]
#define OFF_SCALE  188284928ull        // f32 [4096][158]
#define OFF_OC     190873600ull        // f32 [4096][768]
#define OFF_ORUN   203456512ull        // f32 [4096][768]
#define OFF_MC     216039424ull        // f32 [4096]
#define OFF_LC     216055808ull
#define OFF_MRUN   216072192ull
#define OFF_LRUN   216088576ull
#define OFF_H      216104960ull        // bf16 [4096][768]

__device__ __forceinline__ u16 f2bf(float f) {
    union { float f; unsigned u; } x; x.f = f;
    return (u16)((x.u + 0x7fffu + ((x.u >> 16) & 1u)) >> 16);
}
__device__ __forceinline__ float bf2f_hi(unsigned u) {   // high half as f32
    union { unsigned u; float f; } x; x.u = u & 0xffff0000u; return x.f;
}
__device__ __forceinline__ float bf2f_lo(unsigned u) {   // low half as f32
    union { unsigned u; float f; } x; x.u = u << 16; return x.f;
}

// ---------------- K0a: elementwise f32 -> bf16 cast ----------------
__global__ __launch_bounds__(256) void cast_bf16(const float* __restrict__ src,
                                                 u16* __restrict__ dst, int n4) {
    int i = blockIdx.x * 256 + threadIdx.x;
    if (i >= n4) return;
    float4 v = ((const float4*)src)[i];
    ushort4 o;
    o.x = f2bf(v.x); o.y = f2bf(v.y); o.z = f2bf(v.z); o.w = f2bf(v.w);
    ((ushort4*)dst)[i] = o;
}

// ---------------- K0b: W_vocab -> bf16 row-major, zero-padded ---------------
__global__ __launch_bounds__(256) void prep_wvb(const float* __restrict__ wv,
                                                u16* __restrict__ wvb, int ntask) {
    int t = blockIdx.x * 256 + threadIdx.x;
    if (t >= ntask) return;
    int v = t / 96, ch = t % 96;
    uint4 pk = {0u, 0u, 0u, 0u};
    if (v < VOCAB) {
        const float* p = wv + (size_t)v * DIM + ch * 8;
        float4 f0 = ((const float4*)p)[0];
        float4 f1 = ((const float4*)p)[1];
        pk.x = (unsigned)f2bf(f0.x) | ((unsigned)f2bf(f0.y) << 16);
        pk.y = (unsigned)f2bf(f0.z) | ((unsigned)f2bf(f0.w) << 16);
        pk.z = (unsigned)f2bf(f1.x) | ((unsigned)f2bf(f1.y) << 16);
        pk.w = (unsigned)f2bf(f1.z) | ((unsigned)f2bf(f1.w) << 16);
    }
    *(uint4*)(wvb + (size_t)v * DIM + ch * 8) = pk;
}

// ------- per-chunk: wvb rows -> blocked transposed [tb][768][32] ------------
__global__ __launch_bounds__(256) void prep_wvt_chunk(const u16* __restrict__ wvb,
                                                      u16* __restrict__ wvtc, int v0) {
    __shared__ u16 tile[32][776];
    int tb = blockIdx.x;
    int tid = threadIdx.x;
    int vb = v0 + tb * 32;
    #pragma unroll
    for (int it = 0; it < 12; ++it) {
        int task = tid + 256 * it;
        int row = task / 96, ch = task % 96;
        uint4 pk = *(const uint4*)(wvb + (size_t)(vb + row) * DIM + ch * 8);
        *(uint4*)(&tile[row][ch * 8]) = pk;
    }
    __syncthreads();
    #pragma unroll
    for (int it = 0; it < 12; ++it) {
        int task = tid + 256 * it;
        int d = task >> 2, vc = task & 3;
        u16 t8[8];
        #pragma unroll
        for (int j = 0; j < 8; ++j) t8[j] = tile[vc * 8 + j][d];
        uint4 pk;
        pk.x = (unsigned)t8[0] | ((unsigned)t8[1] << 16);
        pk.y = (unsigned)t8[2] | ((unsigned)t8[3] << 16);
        pk.z = (unsigned)t8[4] | ((unsigned)t8[5] << 16);
        pk.w = (unsigned)t8[6] | ((unsigned)t8[7] << 16);
        *(uint4*)(wvtc + (size_t)tb * 24576 + d * 32 + vc * 8) = pk;
    }
}

// -------- GEMM1: logits tile -> P = exp(z - m_64tile) bf16 + aux(m,l) -------
// grid nt*32: m = bid&31, n = bid>>5. 128x128 tile, K=768.
__global__ __launch_bounds__(256, 2) void gemm1(
    const u16* __restrict__ xb, const u16* __restrict__ wvb,
    const float* __restrict__ bvocab,
    u16* __restrict__ P, float2* __restrict__ aux, int v0, int pitch) {
    __shared__ u16 At[128 * 40];
    __shared__ u16 Bt[128 * 40];
    __shared__ u16 Ptile[128 * 136];
    int mb = blockIdx.x & 31, nb = blockIdx.x >> 5;
    int tid = threadIdx.x;
    int w = tid >> 6, lane = tid & 63, q = lane >> 4, c = lane & 15;
    int wm = w & 1, wn = w >> 1;
    f32x4 acc[4][4];
    #pragma unroll
    for (int i = 0; i < 4; ++i)
        #pragma unroll
        for (int j = 0; j < 4; ++j) acc[i][j] = (f32x4){0.f, 0.f, 0.f, 0.f};

    for (int ko = 0; ko < 24; ++ko) {
        #pragma unroll
        for (int it = 0; it < 2; ++it) {
            int task = tid + 256 * it;
            int row = task >> 2, ch = task & 3;
            *(uint4*)(At + row * 40 + ch * 8) =
                *(const uint4*)(xb + (size_t)(mb * 128 + row) * DIM + ko * 32 + ch * 8);
            *(uint4*)(Bt + row * 40 + ch * 8) =
                *(const uint4*)(wvb + (size_t)(v0 + nb * 128 + row) * DIM + ko * 32 + ch * 8);
        }
        __syncthreads();
        s16x8 af[4], bf[4];
        #pragma unroll
        for (int i = 0; i < 4; ++i)
            af[i] = *(const s16x8*)(At + (wm * 64 + i * 16 + c) * 40 + q * 8);
        #pragma unroll
        for (int j = 0; j < 4; ++j)
            bf[j] = *(const s16x8*)(Bt + (wn * 64 + j * 16 + c) * 40 + q * 8);
        #pragma unroll
        for (int i = 0; i < 4; ++i)
            #pragma unroll
            for (int j = 0; j < 4; ++j)
                acc[i][j] = __builtin_amdgcn_mfma_f32_16x16x32_bf16(af[i], bf[j], acc[i][j], 0, 0, 0);
        __syncthreads();
    }
    // epilogue: bias, per-row 64-col max/sumexp, P bf16 via LDS bounce
    float bvv[4]; bool vok[4];
    #pragma unroll
    for (int j = 0; j < 4; ++j) {
        int v = v0 + nb * 128 + wn * 64 + j * 16 + c;
        vok[j] = (v < VOCAB);
        bvv[j] = vok[j] ? bvocab[v] : 0.f;
    }
    #pragma unroll
    for (int i = 0; i < 4; ++i) {
        #pragma unroll
        for (int jr = 0; jr < 4; ++jr) {
            float z[4];
            #pragma unroll
            for (int j = 0; j < 4; ++j)
                z[j] = vok[j] ? (acc[i][j][jr] + bvv[j]) : -3.0e38f;
            float mx = fmaxf(fmaxf(z[0], z[1]), fmaxf(z[2], z[3]));
            mx = fmaxf(mx, __shfl_xor(mx, 1));
            mx = fmaxf(mx, __shfl_xor(mx, 2));
            mx = fmaxf(mx, __shfl_xor(mx, 4));
            mx = fmaxf(mx, __shfl_xor(mx, 8));
            float e[4], sum = 0.f;
            #pragma unroll
            for (int j = 0; j < 4; ++j) { e[j] = __expf(z[j] - mx); sum += e[j]; }
            sum += __shfl_xor(sum, 1);
            sum += __shfl_xor(sum, 2);
            sum += __shfl_xor(sum, 4);
            sum += __shfl_xor(sum, 8);
            int row = wm * 64 + i * 16 + q * 4 + jr;
            #pragma unroll
            for (int j = 0; j < 4; ++j)
                Ptile[row * 136 + wn * 64 + j * 16 + c] = f2bf(e[j]);
            if (c == 0) {
                float2 ml; ml.x = mx; ml.y = sum;
                aux[(size_t)(mb * 128 + row) * SCALE_PITCH + (nb * 2 + wn)] = ml;
            }
        }
    }
    __syncthreads();
    #pragma unroll
    for (int it = 0; it < 8; ++it) {
        int task = tid + 256 * it;
        int row = task >> 4, ch = task & 15;
        uint4 pk = *(const uint4*)(Ptile + row * 136 + ch * 8);
        *(uint4*)(P + (size_t)(mb * 128 + row) * pitch + nb * 128 + ch * 8) = pk;
    }
}

// -------- reduce (m,l) over chunk tiles -> Mc, Lc, scale ----------
__global__ __launch_bounds__(256) void reduce_ml(const float2* __restrict__ aux,
                                                 float* __restrict__ scale,
                                                 float* __restrict__ Mc,
                                                 float* __restrict__ Lc, int nt2) {
    __shared__ float redm[4];
    __shared__ float reds[4];
    int r = blockIdx.x, tid = threadIdx.x;
    float m = -3.0e38f, l = 0.f;
    if (tid < nt2) {
        float2 a = aux[(size_t)r * SCALE_PITCH + tid];
        m = a.x; l = a.y;
    }
    float mm = m;
    #pragma unroll
    for (int msk = 1; msk < 64; msk <<= 1) mm = fmaxf(mm, __shfl_xor(mm, msk));
    if ((tid & 63) == 0) redm[tid >> 6] = mm;
    __syncthreads();
    float M = fmaxf(fmaxf(redm[0], redm[1]), fmaxf(redm[2], redm[3]));
    float part = 0.f;
    if (tid < nt2) {
        float s = __expf(m - M);
        scale[(size_t)r * SCALE_PITCH + tid] = s;
        part = l * s;
    }
    #pragma unroll
    for (int msk = 1; msk < 64; msk <<= 1) part += __shfl_xor(part, msk);
    if ((tid & 63) == 0) reds[tid >> 6] = part;
    __syncthreads();
    if (tid == 0) {
        Mc[r] = M;
        Lc[r] = reds[0] + reds[1] + reds[2] + reds[3];
    }
}

// -------- GEMM2: Oc += (P*scale) @ Wv_chunk  (split-K, atomic f32) ----------
// grid 1536: m = bid&31; n = (bid>>5)%6; s = (bid>>5)/6
__global__ __launch_bounds__(256, 2) void gemm2(
    const u16* __restrict__ P, const u16* __restrict__ wvtc,
    const float* __restrict__ scale, float* __restrict__ Oc,
    int pitch, int kt32_total, int kts) {
    __shared__ u16 At[128 * 40];
    __shared__ u16 Bt[128 * 40];
    int mb = blockIdx.x & 31;
    int rest = blockIdx.x >> 5;
    int nb = rest % 6, s = rest / 6;
    int kt0 = s * kts;
    int kt1 = kt0 + kts; if (kt1 > kt32_total) kt1 = kt32_total;
    int tid = threadIdx.x;
    int w = tid >> 6, lane = tid & 63, q = lane >> 4, c = lane & 15;
    int wm = w & 1, wn = w >> 1;
    f32x4 acc[4][4];
    #pragma unroll
    for (int i = 0; i < 4; ++i)
        #pragma unroll
        for (int j = 0; j < 4; ++j) acc[i][j] = (f32x4){0.f, 0.f, 0.f, 0.f};

    for (int kt = kt0; kt < kt1; ++kt) {
        #pragma unroll
        for (int it = 0; it < 2; ++it) {
            int task = tid + 256 * it;
            int row = task >> 2, ch = task & 3;
            int gk = kt * 32 + ch * 8;
            size_t rb = (size_t)(mb * 128 + row);
            uint4 raw = *(const uint4*)(P + rb * pitch + gk);
            float sc = scale[rb * SCALE_PITCH + (gk >> 6)];
            unsigned o[4];
            unsigned* rw = (unsigned*)&raw;
            #pragma unroll
            for (int w4 = 0; w4 < 4; ++w4) {
                float lo = bf2f_lo(rw[w4]) * sc;
                float hi = bf2f_hi(rw[w4]) * sc;
                o[w4] = (unsigned)f2bf(lo) | ((unsigned)f2bf(hi) << 16);
            }
            *(uint4*)(At + row * 40 + ch * 8) = *(uint4*)o;
            *(uint4*)(Bt + row * 40 + ch * 8) =
                *(const uint4*)(wvtc + (size_t)kt * 24576 + (nb * 128 + row) * 32 + ch * 8);
        }
        __syncthreads();
        s16x8 af[4], bf[4];
        #pragma unroll
        for (int i = 0; i < 4; ++i)
            af[i] = *(const s16x8*)(At + (wm * 64 + i * 16 + c) * 40 + q * 8);
        #pragma unroll
        for (int j = 0; j < 4; ++j)
            bf[j] = *(const s16x8*)(Bt + (wn * 64 + j * 16 + c) * 40 + q * 8);
        #pragma unroll
        for (int i = 0; i < 4; ++i)
            #pragma unroll
            for (int j = 0; j < 4; ++j)
                acc[i][j] = __builtin_amdgcn_mfma_f32_16x16x32_bf16(af[i], bf[j], acc[i][j], 0, 0, 0);
        __syncthreads();
    }
    #pragma unroll
    for (int i = 0; i < 4; ++i)
        #pragma unroll
        for (int j = 0; j < 4; ++j)
            #pragma unroll
            for (int jr = 0; jr < 4; ++jr) {
                int row = mb * 128 + wm * 64 + i * 16 + q * 4 + jr;
                int col = nb * 128 + wn * 64 + j * 16 + c;
                atomicAdd(&Oc[(size_t)row * DIM + col], acc[i][j][jr]);
            }
}

// -------- merge chunk O into running O (flash-style) ----------
__global__ __launch_bounds__(256) void merge_o(const float* __restrict__ Oc,
                                               float* __restrict__ Orun,
                                               const float* __restrict__ Mc,
                                               const float* __restrict__ Mrun,
                                               int first) {
    int idx = blockIdx.x * 256 + threadIdx.x;
    if (idx >= M_ROWS * DIM) return;
    int r = idx / DIM;
    if (first) {
        Orun[idx] = Oc[idx];
    } else {
        float mr = Mrun[r], mc = Mc[r];
        float Mp = fmaxf(mr, mc);
        Orun[idx] = Orun[idx] * __expf(mr - Mp) + Oc[idx] * __expf(mc - Mp);
    }
}

__global__ __launch_bounds__(256) void update_ml(const float* __restrict__ Mc,
                                                 const float* __restrict__ Lc,
                                                 float* __restrict__ Mrun,
                                                 float* __restrict__ Lrun,
                                                 int first) {
    int r = blockIdx.x * 256 + threadIdx.x;
    if (r >= M_ROWS) return;
    if (first) {
        Mrun[r] = Mc[r]; Lrun[r] = Lc[r];
    } else {
        float mr = Mrun[r], mc = Mc[r];
        float Mp = fmaxf(mr, mc);
        Lrun[r] = Lrun[r] * __expf(mr - Mp) + Lc[r] * __expf(mc - Mp);
        Mrun[r] = Mp;
    }
}

__global__ __launch_bounds__(256) void final_h(const float* __restrict__ Orun,
                                               const float* __restrict__ Lrun,
                                               u16* __restrict__ h) {
    int idx = blockIdx.x * 256 + threadIdx.x;
    if (idx >= M_ROWS * DIM) return;
    int r = idx / DIM;
    h[idx] = f2bf(Orun[idx] / Lrun[r]);
}

// ---------------- K3: out = h @ W_lin^T + b_lin ----------------
__global__ __launch_bounds__(256) void final_gemm(const u16* __restrict__ h,
                                                  const u16* __restrict__ wlb,
                                                  const float* __restrict__ blin,
                                                  float* __restrict__ out) {
    __shared__ u16 At[128 * 40];
    __shared__ u16 Bt[128 * 40];
    int mb = blockIdx.x & 31, eb = blockIdx.x >> 5;
    int tid = threadIdx.x;
    int w = tid >> 6, lane = tid & 63, q = lane >> 4, c = lane & 15;
    int wm = w & 1, wn = w >> 1;
    f32x4 acc[4][4];
    #pragma unroll
    for (int i = 0; i < 4; ++i)
        #pragma unroll
        for (int j = 0; j < 4; ++j) acc[i][j] = (f32x4){0.f, 0.f, 0.f, 0.f};

    for (int ko = 0; ko < 24; ++ko) {
        #pragma unroll
        for (int it = 0; it < 2; ++it) {
            int task = tid + 256 * it;
            int row = task >> 2, ch = task & 3;
            *(uint4*)(At + row * 40 + ch * 8) =
                *(const uint4*)(h + (size_t)(mb * 128 + row) * DIM + ko * 32 + ch * 8);
            *(uint4*)(Bt + row * 40 + ch * 8) =
                *(const uint4*)(wlb + (size_t)(eb * 128 + row) * DIM + ko * 32 + ch * 8);
        }
        __syncthreads();
        s16x8 af[4], bf[4];
        #pragma unroll
        for (int i = 0; i < 4; ++i)
            af[i] = *(const s16x8*)(At + (wm * 64 + i * 16 + c) * 40 + q * 8);
        #pragma unroll
        for (int j = 0; j < 4; ++j)
            bf[j] = *(const s16x8*)(Bt + (wn * 64 + j * 16 + c) * 40 + q * 8);
        #pragma unroll
        for (int i = 0; i < 4; ++i)
            #pragma unroll
            for (int j = 0; j < 4; ++j)
                acc[i][j] = __builtin_amdgcn_mfma_f32_16x16x32_bf16(af[i], bf[j], acc[i][j], 0, 0, 0);
        __syncthreads();
    }
    #pragma unroll
    for (int j = 0; j < 4; ++j) {
        int e = eb * 128 + wn * 64 + j * 16 + c;
        float bl = blin[e];
        #pragma unroll
        for (int i = 0; i < 4; ++i) {
            #pragma unroll
            for (int jr = 0; jr < 4; ++jr) {
                int row = mb * 128 + wm * 64 + i * 16 + q * 4 + jr;
                out[(size_t)row * DIM + e] = acc[i][j][jr] + bl;
            }
        }
    }
}

extern "C" void kernel_launch(void* const* d_in, const int* in_sizes, int n_in,
                              void* d_out, int out_size, void* d_ws, size_t ws_size,
                              hipStream_t stream) {
    const float* x  = (const float*)d_in[0];
    const float* Wv = (const float*)d_in[1];
    const float* bv = (const float*)d_in[2];
    const float* Wl = (const float*)d_in[3];
    const float* bl = (const float*)d_in[4];
    float* out = (float*)d_out;
    char* ws = (char*)d_ws;

    u16* xb   = (u16*)(ws + OFF_XB);
    u16* wlb  = (u16*)(ws + OFF_WLB);
    u16* wvb  = (u16*)(ws + OFF_WVB);
    u16* wvtc = (u16*)(ws + OFF_WVTC);
    u16* P    = (u16*)(ws + OFF_P);
    float2* aux  = (float2*)(ws + OFF_AUX);
    float* scale = (float*)(ws + OFF_SCALE);
    float* Oc    = (float*)(ws + OFF_OC);
    float* Orun  = (float*)(ws + OFF_ORUN);
    float* Mc    = (float*)(ws + OFF_MC);
    float* Lc    = (float*)(ws + OFF_LC);
    float* Mrun  = (float*)(ws + OFF_MRUN);
    float* Lrun  = (float*)(ws + OFF_LRUN);
    u16* h       = (u16*)(ws + OFF_H);

    cast_bf16<<<(M_ROWS * DIM / 4 + 255) / 256, 256, 0, stream>>>(x, xb, M_ROWS * DIM / 4);
    cast_bf16<<<(DIM * DIM / 4 + 255) / 256, 256, 0, stream>>>(Wl, wlb, DIM * DIM / 4);
    {
        int ntask = VPAD * 96;
        prep_wvb<<<(ntask + 255) / 256, 256, 0, stream>>>(Wv, wvb, ntask);
    }

    const int chunk_start[5] = {0, 79, 158, 237, 316};
    const int chunk_nt[5]    = {79, 79, 79, 79, 77};
    for (int cidx = 0; cidx < 5; ++cidx) {
        int nt = chunk_nt[cidx];
        int v0 = chunk_start[cidx] * 128;
        int pitch = nt * 128;
        int nt2 = nt * 2;
        int kt32 = nt * 4;
        int kts = (kt32 + 7) / 8;
        prep_wvt_chunk<<<nt * 4, 256, 0, stream>>>(wvb, wvtc, v0);
        gemm1<<<nt * 32, 256, 0, stream>>>(xb, wvb, bv, P, aux, v0, pitch);
        reduce_ml<<<M_ROWS, 256, 0, stream>>>(aux, scale, Mc, Lc, nt2);
        hipMemsetAsync(Oc, 0, (size_t)M_ROWS * DIM * 4, stream);
        gemm2<<<1536, 256, 0, stream>>>(P, wvtc, scale, Oc, pitch, kt32, kts);
        merge_o<<<(M_ROWS * DIM + 255) / 256, 256, 0, stream>>>(Oc, Orun, Mc, Mrun, cidx == 0);
        update_ml<<<(M_ROWS + 255) / 256, 256, 0, stream>>>(Mc, Lc, Mrun, Lrun, cidx == 0);
    }
    final_h<<<(M_ROWS * DIM + 255) / 256, 256, 0, stream>>>(Orun, Lrun, h);
    final_gemm<<<192, 256, 0, stream>>>(h, wlb, bl, out);
}

// Round 6
// 1466.106 us; speedup vs baseline: 3.2853x; 1.2033x over previous
//
#include <hip/hip_runtime.h>
#include <hip/hip_bf16.h>
#include <stdint.h>

typedef float f32x4 __attribute__((ext_vector_type(4)));
typedef short s16x8 __attribute__((ext_vector_type(8)));
typedef unsigned short u16;

#define M_ROWS 4096
#define DIM    768
#define VOCAB  50257
#define VPAD   50304           // 393 * 128

// ws layout (bytes) — total ~202 MB (< 269 MB proven-safe)
#define OFF_XB     0ull                // bf16 [4096][768]
#define OFF_WLB    6291456ull          // bf16 [768][768]
#define OFF_WVB    7471104ull          // bf16 [50304][768]
#define OFF_WVTC   84738048ull         // bf16 [<=316][768][32] per-chunk transposed
#define OFF_P      100270080ull        // bf16 [4096][<=10112] chunk P
#define OFF_ORUN   183107584ull        // f32 [4096][768]
#define OFF_LROW   195690496ull        // f32 [4096]
#define OFF_BROW   195706880ull        // f32 [4096]
#define OFF_KEYS   195723264ull        // uint[2]: {WnKey, bmaxKey}
#define OFF_H      195723392ull        // bf16 [4096][768]

__device__ __forceinline__ u16 f2bf(float f) {
    union { float f; unsigned u; } x; x.f = f;
    return (u16)((x.u + 0x7fffu + ((x.u >> 16) & 1u)) >> 16);
}
__device__ __forceinline__ float bf2f_hi(unsigned u) {
    union { unsigned u; float f; } x; x.u = u & 0xffff0000u; return x.f;
}
__device__ __forceinline__ float bf2f_lo(unsigned u) {
    union { unsigned u; float f; } x; x.u = u << 16; return x.f;
}
// order-preserving float<->uint key (for atomicMax over signed floats)
__device__ __forceinline__ unsigned fkey(float f) {
    union { float f; unsigned u; } x; x.f = f;
    return (x.u & 0x80000000u) ? ~x.u : (x.u | 0x80000000u);
}
__device__ __forceinline__ float fkey_dec(unsigned k) {
    union { unsigned u; float f; } x;
    x.u = (k & 0x80000000u) ? (k & 0x7fffffffu) : ~k;
    return x.f;
}

// ---------------- K0a: elementwise f32 -> bf16 cast ----------------
__global__ __launch_bounds__(256) void cast_bf16(const float* __restrict__ src,
                                                 u16* __restrict__ dst, int n4) {
    int i = blockIdx.x * 256 + threadIdx.x;
    if (i >= n4) return;
    float4 v = ((const float4*)src)[i];
    ushort4 o;
    o.x = f2bf(v.x); o.y = f2bf(v.y); o.z = f2bf(v.z); o.w = f2bf(v.w);
    ((ushort4*)dst)[i] = o;
}

// ---------------- K0b: W_vocab -> bf16 row-major, zero-padded ---------------
__global__ __launch_bounds__(256) void prep_wvb(const float* __restrict__ wv,
                                                u16* __restrict__ wvb, int ntask) {
    int t = blockIdx.x * 256 + threadIdx.x;
    if (t >= ntask) return;
    int v = t / 96, ch = t % 96;
    uint4 pk = {0u, 0u, 0u, 0u};
    if (v < VOCAB) {
        const float* p = wv + (size_t)v * DIM + ch * 8;
        float4 f0 = ((const float4*)p)[0];
        float4 f1 = ((const float4*)p)[1];
        pk.x = (unsigned)f2bf(f0.x) | ((unsigned)f2bf(f0.y) << 16);
        pk.y = (unsigned)f2bf(f0.z) | ((unsigned)f2bf(f0.w) << 16);
        pk.z = (unsigned)f2bf(f1.x) | ((unsigned)f2bf(f1.y) << 16);
        pk.w = (unsigned)f2bf(f1.z) | ((unsigned)f2bf(f1.w) << 16);
    }
    *(uint4*)(wvb + (size_t)v * DIM + ch * 8) = pk;
}

// ---------------- key init + norm/max kernels for the bound B_r -------------
__global__ void init_keys(unsigned* keys) {
    keys[0] = 0u;                  // Wn >= 0, raw-uint compare
    keys[1] = fkey(-3.0e38f);      // bmax
}

__global__ __launch_bounds__(256) void wnorm(const u16* __restrict__ wvb,
                                             unsigned* __restrict__ keys) {
    __shared__ float part[128];
    int tid = threadIdx.x;
    int vb = blockIdx.x * 32;
    int vl = tid & 31, cg = tid >> 5;
    float s = 0.f;
    #pragma unroll
    for (int it = 0; it < 12; ++it) {
        int ch = cg + 8 * it;
        uint4 pk = *(const uint4*)(wvb + (size_t)(vb + vl) * DIM + ch * 8);
        const unsigned* pw = (const unsigned*)&pk;
        #pragma unroll
        for (int k = 0; k < 4; ++k) {
            float lo = bf2f_lo(pw[k]), hi = bf2f_hi(pw[k]);
            s += lo * lo + hi * hi;
        }
    }
    s += __shfl_xor(s, 32);
    int w = tid >> 6, lane = tid & 63;
    if (lane < 32) part[w * 32 + lane] = s;
    __syncthreads();
    if (tid < 32) {
        float t = part[tid] + part[32 + tid] + part[64 + tid] + part[96 + tid];
        float n = sqrtf(t);
        #pragma unroll
        for (int msk = 1; msk < 32; msk <<= 1) n = fmaxf(n, __shfl_xor(n, msk));
        if (tid == 0) atomicMax(&keys[0], __float_as_uint(n));
    }
}

__global__ __launch_bounds__(256) void bmax_k(const float* __restrict__ bv,
                                              unsigned* __restrict__ keys) {
    int i = blockIdx.x * 256 + threadIdx.x;
    float v = (i < VOCAB) ? bv[i] : -3.0e38f;
    #pragma unroll
    for (int msk = 1; msk < 64; msk <<= 1) v = fmaxf(v, __shfl_xor(v, msk));
    if ((threadIdx.x & 63) == 0) atomicMax(&keys[1], fkey(v));
}

__global__ __launch_bounds__(256) void xnorm(const float* __restrict__ x,
                                             const unsigned* __restrict__ keys,
                                             float* __restrict__ Brow) {
    int w = threadIdx.x >> 6, lane = threadIdx.x & 63;
    int r = blockIdx.x * 4 + w;
    const float4* p = (const float4*)(x + (size_t)r * DIM);
    float s = 0.f;
    #pragma unroll
    for (int it = 0; it < 3; ++it) {
        float4 v = p[it * 64 + lane];
        s += v.x * v.x + v.y * v.y + v.z * v.z + v.w * v.w;
    }
    #pragma unroll
    for (int msk = 1; msk < 64; msk <<= 1) s += __shfl_xor(s, msk);
    if (lane == 0) {
        float Wn = __uint_as_float(keys[0]);
        float bm = fkey_dec(keys[1]);
        Brow[r] = sqrtf(s) * Wn * 1.01f + bm + 0.1f;   // safe upper bound on z
    }
}

// ------- per-chunk: wvb rows -> blocked transposed [tb][768][32] ------------
__global__ __launch_bounds__(256) void prep_wvt_chunk(const u16* __restrict__ wvb,
                                                      u16* __restrict__ wvtc, int v0) {
    __shared__ u16 tile[32][776];
    int tb = blockIdx.x;
    int tid = threadIdx.x;
    int vb = v0 + tb * 32;
    #pragma unroll
    for (int it = 0; it < 12; ++it) {
        int task = tid + 256 * it;
        int row = task / 96, ch = task % 96;
        uint4 pk = *(const uint4*)(wvb + (size_t)(vb + row) * DIM + ch * 8);
        *(uint4*)(&tile[row][ch * 8]) = pk;
    }
    __syncthreads();
    #pragma unroll
    for (int it = 0; it < 12; ++it) {
        int task = tid + 256 * it;
        int d = task >> 2, vc = task & 3;
        u16 t8[8];
        #pragma unroll
        for (int j = 0; j < 8; ++j) t8[j] = tile[vc * 8 + j][d];
        uint4 pk;
        pk.x = (unsigned)t8[0] | ((unsigned)t8[1] << 16);
        pk.y = (unsigned)t8[2] | ((unsigned)t8[3] << 16);
        pk.z = (unsigned)t8[4] | ((unsigned)t8[5] << 16);
        pk.w = (unsigned)t8[6] | ((unsigned)t8[7] << 16);
        *(uint4*)(wvtc + (size_t)tb * 24576 + d * 32 + vc * 8) = pk;
    }
}

// -------- GEMM1: P = exp(z - B_row) bf16; row-sums atomically into Lrow -----
__global__ __launch_bounds__(256, 2) void gemm1(
    const u16* __restrict__ xb, const u16* __restrict__ wvb,
    const float* __restrict__ bvocab, const float* __restrict__ Brow,
    u16* __restrict__ P, float* __restrict__ Lrow, int v0, int pitch) {
    __shared__ u16 At[128 * 40];
    __shared__ u16 Bt[128 * 40];
    __shared__ u16 Ptile[128 * 136];
    __shared__ float BL[128];
    int mb = blockIdx.x & 31, nb = blockIdx.x >> 5;
    int tid = threadIdx.x;
    int w = tid >> 6, lane = tid & 63, q = lane >> 4, c = lane & 15;
    int wm = w & 1, wn = w >> 1;
    if (tid < 128) BL[tid] = Brow[mb * 128 + tid];
    f32x4 acc[4][4];
    #pragma unroll
    for (int i = 0; i < 4; ++i)
        #pragma unroll
        for (int j = 0; j < 4; ++j) acc[i][j] = (f32x4){0.f, 0.f, 0.f, 0.f};

    for (int ko = 0; ko < 24; ++ko) {
        #pragma unroll
        for (int it = 0; it < 2; ++it) {
            int task = tid + 256 * it;
            int row = task >> 2, ch = task & 3;
            *(uint4*)(At + row * 40 + ch * 8) =
                *(const uint4*)(xb + (size_t)(mb * 128 + row) * DIM + ko * 32 + ch * 8);
            *(uint4*)(Bt + row * 40 + ch * 8) =
                *(const uint4*)(wvb + (size_t)(v0 + nb * 128 + row) * DIM + ko * 32 + ch * 8);
        }
        __syncthreads();
        s16x8 af[4], bf[4];
        #pragma unroll
        for (int i = 0; i < 4; ++i)
            af[i] = *(const s16x8*)(At + (wm * 64 + i * 16 + c) * 40 + q * 8);
        #pragma unroll
        for (int j = 0; j < 4; ++j)
            bf[j] = *(const s16x8*)(Bt + (wn * 64 + j * 16 + c) * 40 + q * 8);
        #pragma unroll
        for (int i = 0; i < 4; ++i)
            #pragma unroll
            for (int j = 0; j < 4; ++j)
                acc[i][j] = __builtin_amdgcn_mfma_f32_16x16x32_bf16(af[i], bf[j], acc[i][j], 0, 0, 0);
        __syncthreads();
    }
    // epilogue: e = exp(z - B_row); tile row-sum -> atomicAdd(Lrow)
    float bvv[4]; bool vok[4];
    #pragma unroll
    for (int j = 0; j < 4; ++j) {
        int v = v0 + nb * 128 + wn * 64 + j * 16 + c;
        vok[j] = (v < VOCAB);
        bvv[j] = vok[j] ? bvocab[v] : 0.f;
    }
    #pragma unroll
    for (int i = 0; i < 4; ++i) {
        #pragma unroll
        for (int jr = 0; jr < 4; ++jr) {
            int row = wm * 64 + i * 16 + q * 4 + jr;
            float B = BL[row];
            float e[4], sum = 0.f;
            #pragma unroll
            for (int j = 0; j < 4; ++j) {
                float z = acc[i][j][jr] + bvv[j];
                e[j] = vok[j] ? __expf(z - B) : 0.f;
                sum += e[j];
            }
            #pragma unroll
            for (int j = 0; j < 4; ++j)
                Ptile[row * 136 + wn * 64 + j * 16 + c] = f2bf(e[j]);
            sum += __shfl_xor(sum, 1);
            sum += __shfl_xor(sum, 2);
            sum += __shfl_xor(sum, 4);
            sum += __shfl_xor(sum, 8);
            if (c == 0) atomicAdd(&Lrow[mb * 128 + row], sum);
        }
    }
    __syncthreads();
    #pragma unroll
    for (int it = 0; it < 8; ++it) {
        int task = tid + 256 * it;
        int row = task >> 4, ch = task & 15;
        uint4 pk = *(const uint4*)(Ptile + row * 136 + ch * 8);
        *(uint4*)(P + (size_t)(mb * 128 + row) * pitch + nb * 128 + ch * 8) = pk;
    }
}

// -------- GEMM2: Orun += P @ Wv_chunk  (pure GEMM, 4-way split-K atomic) ----
__global__ __launch_bounds__(256, 2) void gemm2(
    const u16* __restrict__ P, const u16* __restrict__ wvtc,
    float* __restrict__ Orun, int pitch, int kt32_total, int kts) {
    __shared__ u16 At[128 * 40];
    __shared__ u16 Bt[128 * 40];
    int mb = blockIdx.x & 31;
    int rest = blockIdx.x >> 5;
    int nb = rest % 6, s = rest / 6;
    int kt0 = s * kts;
    int kt1 = kt0 + kts; if (kt1 > kt32_total) kt1 = kt32_total;
    int tid = threadIdx.x;
    int w = tid >> 6, lane = tid & 63, q = lane >> 4, c = lane & 15;
    int wm = w & 1, wn = w >> 1;
    f32x4 acc[4][4];
    #pragma unroll
    for (int i = 0; i < 4; ++i)
        #pragma unroll
        for (int j = 0; j < 4; ++j) acc[i][j] = (f32x4){0.f, 0.f, 0.f, 0.f};

    for (int kt = kt0; kt < kt1; ++kt) {
        #pragma unroll
        for (int it = 0; it < 2; ++it) {
            int task = tid + 256 * it;
            int row = task >> 2, ch = task & 3;
            *(uint4*)(At + row * 40 + ch * 8) =
                *(const uint4*)(P + (size_t)(mb * 128 + row) * pitch + kt * 32 + ch * 8);
            *(uint4*)(Bt + row * 40 + ch * 8) =
                *(const uint4*)(wvtc + (size_t)kt * 24576 + (nb * 128 + row) * 32 + ch * 8);
        }
        __syncthreads();
        s16x8 af[4], bf[4];
        #pragma unroll
        for (int i = 0; i < 4; ++i)
            af[i] = *(const s16x8*)(At + (wm * 64 + i * 16 + c) * 40 + q * 8);
        #pragma unroll
        for (int j = 0; j < 4; ++j)
            bf[j] = *(const s16x8*)(Bt + (wn * 64 + j * 16 + c) * 40 + q * 8);
        #pragma unroll
        for (int i = 0; i < 4; ++i)
            #pragma unroll
            for (int j = 0; j < 4; ++j)
                acc[i][j] = __builtin_amdgcn_mfma_f32_16x16x32_bf16(af[i], bf[j], acc[i][j], 0, 0, 0);
        __syncthreads();
    }
    #pragma unroll
    for (int i = 0; i < 4; ++i)
        #pragma unroll
        for (int j = 0; j < 4; ++j)
            #pragma unroll
            for (int jr = 0; jr < 4; ++jr) {
                int row = mb * 128 + wm * 64 + i * 16 + q * 4 + jr;
                int col = nb * 128 + wn * 64 + j * 16 + c;
                atomicAdd(&Orun[(size_t)row * DIM + col], acc[i][j][jr]);
            }
}

__global__ __launch_bounds__(256) void final_h(const float* __restrict__ Orun,
                                               const float* __restrict__ Lrow,
                                               u16* __restrict__ h) {
    int idx = blockIdx.x * 256 + threadIdx.x;
    if (idx >= M_ROWS * DIM) return;
    int r = idx / DIM;
    h[idx] = f2bf(Orun[idx] / Lrow[r]);
}

// ---------------- K3: out = h @ W_lin^T + b_lin ----------------
__global__ __launch_bounds__(256) void final_gemm(const u16* __restrict__ h,
                                                  const u16* __restrict__ wlb,
                                                  const float* __restrict__ blin,
                                                  float* __restrict__ out) {
    __shared__ u16 At[128 * 40];
    __shared__ u16 Bt[128 * 40];
    int mb = blockIdx.x & 31, eb = blockIdx.x >> 5;
    int tid = threadIdx.x;
    int w = tid >> 6, lane = tid & 63, q = lane >> 4, c = lane & 15;
    int wm = w & 1, wn = w >> 1;
    f32x4 acc[4][4];
    #pragma unroll
    for (int i = 0; i < 4; ++i)
        #pragma unroll
        for (int j = 0; j < 4; ++j) acc[i][j] = (f32x4){0.f, 0.f, 0.f, 0.f};

    for (int ko = 0; ko < 24; ++ko) {
        #pragma unroll
        for (int it = 0; it < 2; ++it) {
            int task = tid + 256 * it;
            int row = task >> 2, ch = task & 3;
            *(uint4*)(At + row * 40 + ch * 8) =
                *(const uint4*)(h + (size_t)(mb * 128 + row) * DIM + ko * 32 + ch * 8);
            *(uint4*)(Bt + row * 40 + ch * 8) =
                *(const uint4*)(wlb + (size_t)(eb * 128 + row) * DIM + ko * 32 + ch * 8);
        }
        __syncthreads();
        s16x8 af[4], bf[4];
        #pragma unroll
        for (int i = 0; i < 4; ++i)
            af[i] = *(const s16x8*)(At + (wm * 64 + i * 16 + c) * 40 + q * 8);
        #pragma unroll
        for (int j = 0; j < 4; ++j)
            bf[j] = *(const s16x8*)(Bt + (wn * 64 + j * 16 + c) * 40 + q * 8);
        #pragma unroll
        for (int i = 0; i < 4; ++i)
            #pragma unroll
            for (int j = 0; j < 4; ++j)
                acc[i][j] = __builtin_amdgcn_mfma_f32_16x16x32_bf16(af[i], bf[j], acc[i][j], 0, 0, 0);
        __syncthreads();
    }
    #pragma unroll
    for (int j = 0; j < 4; ++j) {
        int e = eb * 128 + wn * 64 + j * 16 + c;
        float bl = blin[e];
        #pragma unroll
        for (int i = 0; i < 4; ++i) {
            #pragma unroll
            for (int jr = 0; jr < 4; ++jr) {
                int row = mb * 128 + wm * 64 + i * 16 + q * 4 + jr;
                out[(size_t)row * DIM + e] = acc[i][j][jr] + bl;
            }
        }
    }
}

extern "C" void kernel_launch(void* const* d_in, const int* in_sizes, int n_in,
                              void* d_out, int out_size, void* d_ws, size_t ws_size,
                              hipStream_t stream) {
    const float* x  = (const float*)d_in[0];
    const float* Wv = (const float*)d_in[1];
    const float* bv = (const float*)d_in[2];
    const float* Wl = (const float*)d_in[3];
    const float* bl = (const float*)d_in[4];
    float* out = (float*)d_out;
    char* ws = (char*)d_ws;

    u16* xb   = (u16*)(ws + OFF_XB);
    u16* wlb  = (u16*)(ws + OFF_WLB);
    u16* wvb  = (u16*)(ws + OFF_WVB);
    u16* wvtc = (u16*)(ws + OFF_WVTC);
    u16* P    = (u16*)(ws + OFF_P);
    float* Orun  = (float*)(ws + OFF_ORUN);
    float* Lrow  = (float*)(ws + OFF_LROW);
    float* Brow  = (float*)(ws + OFF_BROW);
    unsigned* keys = (unsigned*)(ws + OFF_KEYS);
    u16* h       = (u16*)(ws + OFF_H);

    cast_bf16<<<(M_ROWS * DIM / 4 + 255) / 256, 256, 0, stream>>>(x, xb, M_ROWS * DIM / 4);
    cast_bf16<<<(DIM * DIM / 4 + 255) / 256, 256, 0, stream>>>(Wl, wlb, DIM * DIM / 4);
    {
        int ntask = VPAD * 96;
        prep_wvb<<<(ntask + 255) / 256, 256, 0, stream>>>(Wv, wvb, ntask);
    }
    init_keys<<<1, 1, 0, stream>>>(keys);
    hipMemsetAsync(Orun, 0, (size_t)M_ROWS * DIM * 4, stream);
    hipMemsetAsync(Lrow, 0, (size_t)M_ROWS * 4, stream);
    wnorm<<<VPAD / 32, 256, 0, stream>>>(wvb, keys);
    bmax_k<<<(VOCAB + 255) / 256, 256, 0, stream>>>(bv, keys);
    xnorm<<<M_ROWS / 4, 256, 0, stream>>>(x, keys, Brow);

    const int chunk_start[5] = {0, 79, 158, 237, 316};
    const int chunk_nt[5]    = {79, 79, 79, 79, 77};
    for (int cidx = 0; cidx < 5; ++cidx) {
        int nt = chunk_nt[cidx];
        int v0 = chunk_start[cidx] * 128;
        int pitch = nt * 128;
        int kt32 = nt * 4;
        int kts = (kt32 + 3) / 4;
        prep_wvt_chunk<<<nt * 4, 256, 0, stream>>>(wvb, wvtc, v0);
        gemm1<<<nt * 32, 256, 0, stream>>>(xb, wvb, bv, Brow, P, Lrow, v0, pitch);
        gemm2<<<32 * 6 * 4, 256, 0, stream>>>(P, wvtc, Orun, pitch, kt32, kts);
    }
    final_h<<<(M_ROWS * DIM + 255) / 256, 256, 0, stream>>>(Orun, Lrow, h);
    final_gemm<<<192, 256, 0, stream>>>(h, wlb, bl, out);
}

// Round 7
// 1271.461 us; speedup vs baseline: 3.7883x; 1.1531x over previous
//
#include <hip/hip_runtime.h>
#include <hip/hip_bf16.h>
#include <stdint.h>

typedef float f32x4 __attribute__((ext_vector_type(4)));
typedef short s16x8 __attribute__((ext_vector_type(8)));
typedef unsigned short u16;

#define M_ROWS 4096
#define DIM    768
#define VOCAB  50257
#define VPAD   50304           // 393 * 128

// ws layout (bytes) — total ~202 MB (< 269 MB proven-safe)
#define OFF_XB     0ull                // bf16 [4096][768]
#define OFF_WLB    6291456ull          // bf16 [768][768]
#define OFF_WVB    7471104ull          // bf16 [50304][768]
#define OFF_WVTC   84738048ull         // bf16 [<=316][768][32] per-chunk transposed
#define OFF_P      100270080ull        // bf16 [4096][<=10112] chunk P
#define OFF_ORUN   183107584ull        // f32 [4096][768]
#define OFF_LROW   195690496ull        // f32 [4096]
#define OFF_BROW   195706880ull        // f32 [4096]
#define OFF_KEYS   195723264ull        // uint[2]: {WnKey, bmaxKey}
#define OFF_H      195723392ull        // bf16 [4096][768]

__device__ __forceinline__ u16 f2bf(float f) {
    union { float f; unsigned u; } x; x.f = f;
    return (u16)((x.u + 0x7fffu + ((x.u >> 16) & 1u)) >> 16);
}
__device__ __forceinline__ float bf2f_hi(unsigned u) {
    union { unsigned u; float f; } x; x.u = u & 0xffff0000u; return x.f;
}
__device__ __forceinline__ float bf2f_lo(unsigned u) {
    union { unsigned u; float f; } x; x.u = u << 16; return x.f;
}
__device__ __forceinline__ unsigned fkey(float f) {
    union { float f; unsigned u; } x; x.f = f;
    return (x.u & 0x80000000u) ? ~x.u : (x.u | 0x80000000u);
}
__device__ __forceinline__ float fkey_dec(unsigned k) {
    union { unsigned u; float f; } x;
    x.u = (k & 0x80000000u) ? (k & 0x7fffffffu) : ~k;
    return x.f;
}
// async 16B global -> LDS (direct-to-shared DMA); LDS dest must be
// wave-uniform-base + lane*16, which holds for dest = base + task*16B
// with task = it*256 + tid.
__device__ __forceinline__ void glds16(const u16* g, u16* l) {
    __builtin_amdgcn_global_load_lds(
        (const __attribute__((address_space(1))) unsigned int*)g,
        (__attribute__((address_space(3))) unsigned int*)l,
        16, 0, 0);
}

// ---------------- K0a: elementwise f32 -> bf16 cast ----------------
__global__ __launch_bounds__(256) void cast_bf16(const float* __restrict__ src,
                                                 u16* __restrict__ dst, int n4) {
    int i = blockIdx.x * 256 + threadIdx.x;
    if (i >= n4) return;
    float4 v = ((const float4*)src)[i];
    ushort4 o;
    o.x = f2bf(v.x); o.y = f2bf(v.y); o.z = f2bf(v.z); o.w = f2bf(v.w);
    ((ushort4*)dst)[i] = o;
}

// ---------------- K0b: W_vocab -> bf16 row-major, zero-padded ---------------
__global__ __launch_bounds__(256) void prep_wvb(const float* __restrict__ wv,
                                                u16* __restrict__ wvb, int ntask) {
    int t = blockIdx.x * 256 + threadIdx.x;
    if (t >= ntask) return;
    int v = t / 96, ch = t % 96;
    uint4 pk = {0u, 0u, 0u, 0u};
    if (v < VOCAB) {
        const float* p = wv + (size_t)v * DIM + ch * 8;
        float4 f0 = ((const float4*)p)[0];
        float4 f1 = ((const float4*)p)[1];
        pk.x = (unsigned)f2bf(f0.x) | ((unsigned)f2bf(f0.y) << 16);
        pk.y = (unsigned)f2bf(f0.z) | ((unsigned)f2bf(f0.w) << 16);
        pk.z = (unsigned)f2bf(f1.x) | ((unsigned)f2bf(f1.y) << 16);
        pk.w = (unsigned)f2bf(f1.z) | ((unsigned)f2bf(f1.w) << 16);
    }
    *(uint4*)(wvb + (size_t)v * DIM + ch * 8) = pk;
}

// ---------------- key init + norm/max kernels for the bound B_r -------------
__global__ void init_keys(unsigned* keys) {
    keys[0] = 0u;
    keys[1] = fkey(-3.0e38f);
}

__global__ __launch_bounds__(256) void wnorm(const u16* __restrict__ wvb,
                                             unsigned* __restrict__ keys) {
    __shared__ float part[128];
    int tid = threadIdx.x;
    int vb = blockIdx.x * 32;
    int vl = tid & 31, cg = tid >> 5;
    float s = 0.f;
    #pragma unroll
    for (int it = 0; it < 12; ++it) {
        int ch = cg + 8 * it;
        uint4 pk = *(const uint4*)(wvb + (size_t)(vb + vl) * DIM + ch * 8);
        const unsigned* pw = (const unsigned*)&pk;
        #pragma unroll
        for (int k = 0; k < 4; ++k) {
            float lo = bf2f_lo(pw[k]), hi = bf2f_hi(pw[k]);
            s += lo * lo + hi * hi;
        }
    }
    s += __shfl_xor(s, 32);
    int w = tid >> 6, lane = tid & 63;
    if (lane < 32) part[w * 32 + lane] = s;
    __syncthreads();
    if (tid < 32) {
        float t = part[tid] + part[32 + tid] + part[64 + tid] + part[96 + tid];
        float n = sqrtf(t);
        #pragma unroll
        for (int msk = 1; msk < 32; msk <<= 1) n = fmaxf(n, __shfl_xor(n, msk));
        if (tid == 0) atomicMax(&keys[0], __float_as_uint(n));
    }
}

__global__ __launch_bounds__(256) void bmax_k(const float* __restrict__ bv,
                                              unsigned* __restrict__ keys) {
    int i = blockIdx.x * 256 + threadIdx.x;
    float v = (i < VOCAB) ? bv[i] : -3.0e38f;
    #pragma unroll
    for (int msk = 1; msk < 64; msk <<= 1) v = fmaxf(v, __shfl_xor(v, msk));
    if ((threadIdx.x & 63) == 0) atomicMax(&keys[1], fkey(v));
}

__global__ __launch_bounds__(256) void xnorm(const float* __restrict__ x,
                                             const unsigned* __restrict__ keys,
                                             float* __restrict__ Brow) {
    int w = threadIdx.x >> 6, lane = threadIdx.x & 63;
    int r = blockIdx.x * 4 + w;
    const float4* p = (const float4*)(x + (size_t)r * DIM);
    float s = 0.f;
    #pragma unroll
    for (int it = 0; it < 3; ++it) {
        float4 v = p[it * 64 + lane];
        s += v.x * v.x + v.y * v.y + v.z * v.z + v.w * v.w;
    }
    #pragma unroll
    for (int msk = 1; msk < 64; msk <<= 1) s += __shfl_xor(s, msk);
    if (lane == 0) {
        float Wn = __uint_as_float(keys[0]);
        float bm = fkey_dec(keys[1]);
        Brow[r] = sqrtf(s) * Wn * 1.01f + bm + 0.1f;
    }
}

// ------- per-chunk: wvb rows -> blocked transposed [tb][768][32] ------------
__global__ __launch_bounds__(256) void prep_wvt_chunk(const u16* __restrict__ wvb,
                                                      u16* __restrict__ wvtc, int v0) {
    __shared__ u16 tile[32][776];
    int tb = blockIdx.x;
    int tid = threadIdx.x;
    int vb = v0 + tb * 32;
    #pragma unroll
    for (int it = 0; it < 12; ++it) {
        int task = tid + 256 * it;
        int row = task / 96, ch = task % 96;
        uint4 pk = *(const uint4*)(wvb + (size_t)(vb + row) * DIM + ch * 8);
        *(uint4*)(&tile[row][ch * 8]) = pk;
    }
    __syncthreads();
    #pragma unroll
    for (int it = 0; it < 12; ++it) {
        int task = tid + 256 * it;
        int d = task >> 2, vc = task & 3;
        u16 t8[8];
        #pragma unroll
        for (int j = 0; j < 8; ++j) t8[j] = tile[vc * 8 + j][d];
        uint4 pk;
        pk.x = (unsigned)t8[0] | ((unsigned)t8[1] << 16);
        pk.y = (unsigned)t8[2] | ((unsigned)t8[3] << 16);
        pk.z = (unsigned)t8[4] | ((unsigned)t8[5] << 16);
        pk.w = (unsigned)t8[6] | ((unsigned)t8[7] << 16);
        *(uint4*)(wvtc + (size_t)tb * 24576 + d * 32 + vc * 8) = pk;
    }
}

// -------- GEMM1: P = exp(z - B_row) bf16; row-sums atomically into Lrow -----
// m97-style: global_load_lds width-16 staging, unpadded [128][32] tiles.
__global__ __launch_bounds__(256, 2) void gemm1(
    const u16* __restrict__ xb, const u16* __restrict__ wvb,
    const float* __restrict__ bvocab, const float* __restrict__ Brow,
    u16* __restrict__ P, float* __restrict__ Lrow, int v0, int pitch) {
    __shared__ u16 SB[17408];          // 34816 B: staging (At 8KB | Bt 8KB); Ptile overlay
    __shared__ float BL[128];
    u16* At = SB;
    u16* Bt = SB + 4096;
    u16* Ptile = SB;                   // [128][136] after K-loop
    int mb = blockIdx.x & 31, nb = blockIdx.x >> 5;
    int tid = threadIdx.x;
    int w = tid >> 6, lane = tid & 63, q = lane >> 4, c = lane & 15;
    int wm = w & 1, wn = w >> 1;
    if (tid < 128) BL[tid] = Brow[mb * 128 + tid];
    int trow = tid >> 2, tch = tid & 3;
    const u16* gA0 = xb + (size_t)(mb * 128 + trow) * DIM + tch * 8;
    const u16* gA1 = xb + (size_t)(mb * 128 + 64 + trow) * DIM + tch * 8;
    const u16* gB0 = wvb + (size_t)(v0 + nb * 128 + trow) * DIM + tch * 8;
    const u16* gB1 = wvb + (size_t)(v0 + nb * 128 + 64 + trow) * DIM + tch * 8;
    f32x4 acc[4][4];
    #pragma unroll
    for (int i = 0; i < 4; ++i)
        #pragma unroll
        for (int j = 0; j < 4; ++j) acc[i][j] = (f32x4){0.f, 0.f, 0.f, 0.f};

    for (int ko = 0; ko < 24; ++ko) {
        glds16(gA0 + ko * 32, At + tid * 8);
        glds16(gA1 + ko * 32, At + (tid + 256) * 8);
        glds16(gB0 + ko * 32, Bt + tid * 8);
        glds16(gB1 + ko * 32, Bt + (tid + 256) * 8);
        __syncthreads();
        s16x8 af[4], bf[4];
        #pragma unroll
        for (int i = 0; i < 4; ++i)
            af[i] = *(const s16x8*)(At + (wm * 64 + i * 16 + c) * 32 + q * 8);
        #pragma unroll
        for (int j = 0; j < 4; ++j)
            bf[j] = *(const s16x8*)(Bt + (wn * 64 + j * 16 + c) * 32 + q * 8);
        #pragma unroll
        for (int i = 0; i < 4; ++i)
            #pragma unroll
            for (int j = 0; j < 4; ++j)
                acc[i][j] = __builtin_amdgcn_mfma_f32_16x16x32_bf16(af[i], bf[j], acc[i][j], 0, 0, 0);
        __syncthreads();
    }
    // epilogue: e = exp(z - B_row); tile row-sum -> atomicAdd(Lrow); P via bounce
    float bvv[4]; bool vok[4];
    #pragma unroll
    for (int j = 0; j < 4; ++j) {
        int v = v0 + nb * 128 + wn * 64 + j * 16 + c;
        vok[j] = (v < VOCAB);
        bvv[j] = vok[j] ? bvocab[v] : 0.f;
    }
    #pragma unroll
    for (int i = 0; i < 4; ++i) {
        #pragma unroll
        for (int jr = 0; jr < 4; ++jr) {
            int row = wm * 64 + i * 16 + q * 4 + jr;
            float B = BL[row];
            float e[4], sum = 0.f;
            #pragma unroll
            for (int j = 0; j < 4; ++j) {
                float z = acc[i][j][jr] + bvv[j];
                e[j] = vok[j] ? __expf(z - B) : 0.f;
                sum += e[j];
            }
            #pragma unroll
            for (int j = 0; j < 4; ++j)
                Ptile[row * 136 + wn * 64 + j * 16 + c] = f2bf(e[j]);
            sum += __shfl_xor(sum, 1);
            sum += __shfl_xor(sum, 2);
            sum += __shfl_xor(sum, 4);
            sum += __shfl_xor(sum, 8);
            if (c == 0) atomicAdd(&Lrow[mb * 128 + row], sum);
        }
    }
    __syncthreads();
    #pragma unroll
    for (int it = 0; it < 8; ++it) {
        int task = tid + 256 * it;
        int row = task >> 4, ch = task & 15;
        uint4 pk = *(const uint4*)(Ptile + row * 136 + ch * 8);
        *(uint4*)(P + (size_t)(mb * 128 + row) * pitch + nb * 128 + ch * 8) = pk;
    }
}

// -------- GEMM2: Orun += P @ Wv_chunk  (4-way split-K atomic) ---------------
__global__ __launch_bounds__(256, 2) void gemm2(
    const u16* __restrict__ P, const u16* __restrict__ wvtc,
    float* __restrict__ Orun, int pitch, int kt32_total, int kts) {
    __shared__ u16 At[4096];
    __shared__ u16 Bt[4096];
    int mb = blockIdx.x & 31;
    int rest = blockIdx.x >> 5;
    int nb = rest % 6, s = rest / 6;
    int kt0 = s * kts;
    int kt1 = kt0 + kts; if (kt1 > kt32_total) kt1 = kt32_total;
    int tid = threadIdx.x;
    int w = tid >> 6, lane = tid & 63, q = lane >> 4, c = lane & 15;
    int wm = w & 1, wn = w >> 1;
    int trow = tid >> 2, tch = tid & 3;
    const u16* gA0 = P + (size_t)(mb * 128 + trow) * pitch + tch * 8;
    const u16* gA1 = P + (size_t)(mb * 128 + 64 + trow) * pitch + tch * 8;
    const u16* gB0 = wvtc + (size_t)(nb * 128 + trow) * 32 + tch * 8;
    const u16* gB1 = wvtc + (size_t)(nb * 128 + 64 + trow) * 32 + tch * 8;
    f32x4 acc[4][4];
    #pragma unroll
    for (int i = 0; i < 4; ++i)
        #pragma unroll
        for (int j = 0; j < 4; ++j) acc[i][j] = (f32x4){0.f, 0.f, 0.f, 0.f};

    for (int kt = kt0; kt < kt1; ++kt) {
        glds16(gA0 + kt * 32, At + tid * 8);
        glds16(gA1 + kt * 32, At + (tid + 256) * 8);
        glds16(gB0 + (size_t)kt * 24576, Bt + tid * 8);
        glds16(gB1 + (size_t)kt * 24576, Bt + (tid + 256) * 8);
        __syncthreads();
        s16x8 af[4], bf[4];
        #pragma unroll
        for (int i = 0; i < 4; ++i)
            af[i] = *(const s16x8*)(At + (wm * 64 + i * 16 + c) * 32 + q * 8);
        #pragma unroll
        for (int j = 0; j < 4; ++j)
            bf[j] = *(const s16x8*)(Bt + (wn * 64 + j * 16 + c) * 32 + q * 8);
        #pragma unroll
        for (int i = 0; i < 4; ++i)
            #pragma unroll
            for (int j = 0; j < 4; ++j)
                acc[i][j] = __builtin_amdgcn_mfma_f32_16x16x32_bf16(af[i], bf[j], acc[i][j], 0, 0, 0);
        __syncthreads();
    }
    #pragma unroll
    for (int i = 0; i < 4; ++i)
        #pragma unroll
        for (int j = 0; j < 4; ++j)
            #pragma unroll
            for (int jr = 0; jr < 4; ++jr) {
                int row = mb * 128 + wm * 64 + i * 16 + q * 4 + jr;
                int col = nb * 128 + wn * 64 + j * 16 + c;
                atomicAdd(&Orun[(size_t)row * DIM + col], acc[i][j][jr]);
            }
}

__global__ __launch_bounds__(256) void final_h(const float* __restrict__ Orun,
                                               const float* __restrict__ Lrow,
                                               u16* __restrict__ h) {
    int idx = blockIdx.x * 256 + threadIdx.x;
    if (idx >= M_ROWS * DIM) return;
    int r = idx / DIM;
    h[idx] = f2bf(Orun[idx] / Lrow[r]);
}

// ---------------- K3: out = h @ W_lin^T + b_lin ----------------
__global__ __launch_bounds__(256, 2) void final_gemm(const u16* __restrict__ h,
                                                     const u16* __restrict__ wlb,
                                                     const float* __restrict__ blin,
                                                     float* __restrict__ out) {
    __shared__ u16 At[4096];
    __shared__ u16 Bt[4096];
    int mb = blockIdx.x & 31, eb = blockIdx.x >> 5;
    int tid = threadIdx.x;
    int w = tid >> 6, lane = tid & 63, q = lane >> 4, c = lane & 15;
    int wm = w & 1, wn = w >> 1;
    int trow = tid >> 2, tch = tid & 3;
    const u16* gA0 = h + (size_t)(mb * 128 + trow) * DIM + tch * 8;
    const u16* gA1 = h + (size_t)(mb * 128 + 64 + trow) * DIM + tch * 8;
    const u16* gB0 = wlb + (size_t)(eb * 128 + trow) * DIM + tch * 8;
    const u16* gB1 = wlb + (size_t)(eb * 128 + 64 + trow) * DIM + tch * 8;
    f32x4 acc[4][4];
    #pragma unroll
    for (int i = 0; i < 4; ++i)
        #pragma unroll
        for (int j = 0; j < 4; ++j) acc[i][j] = (f32x4){0.f, 0.f, 0.f, 0.f};

    for (int ko = 0; ko < 24; ++ko) {
        glds16(gA0 + ko * 32, At + tid * 8);
        glds16(gA1 + ko * 32, At + (tid + 256) * 8);
        glds16(gB0 + ko * 32, Bt + tid * 8);
        glds16(gB1 + ko * 32, Bt + (tid + 256) * 8);
        __syncthreads();
        s16x8 af[4], bf[4];
        #pragma unroll
        for (int i = 0; i < 4; ++i)
            af[i] = *(const s16x8*)(At + (wm * 64 + i * 16 + c) * 32 + q * 8);
        #pragma unroll
        for (int j = 0; j < 4; ++j)
            bf[j] = *(const s16x8*)(Bt + (wn * 64 + j * 16 + c) * 32 + q * 8);
        #pragma unroll
        for (int i = 0; i < 4; ++i)
            #pragma unroll
            for (int j = 0; j < 4; ++j)
                acc[i][j] = __builtin_amdgcn_mfma_f32_16x16x32_bf16(af[i], bf[j], acc[i][j], 0, 0, 0);
        __syncthreads();
    }
    #pragma unroll
    for (int j = 0; j < 4; ++j) {
        int e = eb * 128 + wn * 64 + j * 16 + c;
        float bl = blin[e];
        #pragma unroll
        for (int i = 0; i < 4; ++i) {
            #pragma unroll
            for (int jr = 0; jr < 4; ++jr) {
                int row = mb * 128 + wm * 64 + i * 16 + q * 4 + jr;
                out[(size_t)row * DIM + e] = acc[i][j][jr] + bl;
            }
        }
    }
}

extern "C" void kernel_launch(void* const* d_in, const int* in_sizes, int n_in,
                              void* d_out, int out_size, void* d_ws, size_t ws_size,
                              hipStream_t stream) {
    const float* x  = (const float*)d_in[0];
    const float* Wv = (const float*)d_in[1];
    const float* bv = (const float*)d_in[2];
    const float* Wl = (const float*)d_in[3];
    const float* bl = (const float*)d_in[4];
    float* out = (float*)d_out;
    char* ws = (char*)d_ws;

    u16* xb   = (u16*)(ws + OFF_XB);
    u16* wlb  = (u16*)(ws + OFF_WLB);
    u16* wvb  = (u16*)(ws + OFF_WVB);
    u16* wvtc = (u16*)(ws + OFF_WVTC);
    u16* P    = (u16*)(ws + OFF_P);
    float* Orun  = (float*)(ws + OFF_ORUN);
    float* Lrow  = (float*)(ws + OFF_LROW);
    float* Brow  = (float*)(ws + OFF_BROW);
    unsigned* keys = (unsigned*)(ws + OFF_KEYS);
    u16* h       = (u16*)(ws + OFF_H);

    cast_bf16<<<(M_ROWS * DIM / 4 + 255) / 256, 256, 0, stream>>>(x, xb, M_ROWS * DIM / 4);
    cast_bf16<<<(DIM * DIM / 4 + 255) / 256, 256, 0, stream>>>(Wl, wlb, DIM * DIM / 4);
    {
        int ntask = VPAD * 96;
        prep_wvb<<<(ntask + 255) / 256, 256, 0, stream>>>(Wv, wvb, ntask);
    }
    init_keys<<<1, 1, 0, stream>>>(keys);
    hipMemsetAsync(Orun, 0, (size_t)M_ROWS * DIM * 4, stream);
    hipMemsetAsync(Lrow, 0, (size_t)M_ROWS * 4, stream);
    wnorm<<<VPAD / 32, 256, 0, stream>>>(wvb, keys);
    bmax_k<<<(VOCAB + 255) / 256, 256, 0, stream>>>(bv, keys);
    xnorm<<<M_ROWS / 4, 256, 0, stream>>>(x, keys, Brow);

    const int chunk_start[5] = {0, 79, 158, 237, 316};
    const int chunk_nt[5]    = {79, 79, 79, 79, 77};
    for (int cidx = 0; cidx < 5; ++cidx) {
        int nt = chunk_nt[cidx];
        int v0 = chunk_start[cidx] * 128;
        int pitch = nt * 128;
        int kt32 = nt * 4;
        int kts = (kt32 + 3) / 4;
        prep_wvt_chunk<<<nt * 4, 256, 0, stream>>>(wvb, wvtc, v0);
        gemm1<<<nt * 32, 256, 0, stream>>>(xb, wvb, bv, Brow, P, Lrow, v0, pitch);
        gemm2<<<32 * 6 * 4, 256, 0, stream>>>(P, wvtc, Orun, pitch, kt32, kts);
    }
    final_h<<<(M_ROWS * DIM + 255) / 256, 256, 0, stream>>>(Orun, Lrow, h);
    final_gemm<<<192, 256, 0, stream>>>(h, wlb, bl, out);
}